// Round 13
// baseline (245.430 us; speedup 1.0000x reference)
//
#include <hip/hip_runtime.h>

typedef __attribute__((ext_vector_type(8))) short bf16x8;
typedef __attribute__((ext_vector_type(4))) float f32x4;

#define THR 256
#define PBLK 32

__device__ __forceinline__ unsigned int bf_rne(float f) {
    unsigned int u = __float_as_uint(f);
    u += 0x7fffu + ((u >> 16) & 1u);
    return u >> 16;
}

#define MFMA(A, B, C) __builtin_amdgcn_mfma_f32_16x16x32_bf16((A), (B), (C), 0, 0, 0)

// xb u16 index: j-stride 520, slot XOR'd with ig/pl/jq (A-reads/writes ~2-way)
#define XB(ti, j, pl, slot) ((ti) * 8320 + (j) * 520 + (pl) * 32 + (slot) * 8)

__global__ __launch_bounds__(THR) void equi_mfma(
    const float* __restrict__ x_mv,    // [Np,32,16]
    const float* __restrict__ x_s,     // [Np,64]
    const float* __restrict__ skip_mv, // [Nc,32,16]
    const float* __restrict__ skip_s,  // [Nc,64]
    const float* __restrict__ w_mv,    // [32,32,9]
    const float* __restrict__ w_s2mv,  // [32,64]
    const float* __restrict__ w_mv2s,  // [64,32]
    const float* __restrict__ w_s2s,   // [64,64]
    const float* __restrict__ b_s,     // [64]
    float* __restrict__ out_mv,        // [Nc,32,16]
    float* __restrict__ out_s,         // [Nc,64]
    int n_parent, int stride)
{
    // LDS: staging only. xb 33280 B + xsb 4096 B = 37376 B -> 4 blocks/CU.
    __shared__ char smem[37376];
    unsigned short* xb  = (unsigned short*)smem;
    unsigned short* xsb = (unsigned short*)(smem + 33280);

    const int t  = threadIdx.x;
    const int p0 = blockIdx.x * PBLK;

    // ---- stage x_mv -> xb: thread = (p, ig2, jq); 16 f4 loads -> 8 ds_write_b128 ----
    {
        const int p   = t >> 3;
        const int ig2 = (t >> 2) & 1;
        const int jq  = t & 3;
        const int ti  = p >> 4, pl = p & 15;
        const float4* xg = (const float4*)(x_mv + (size_t)p0 * 512);
        const int base = p * 128 + ig2 * 64 + jq;
        bf16x8 acc[4][2];     // [jo][igl]
        #pragma unroll
        for (int s = 0; s < 16; ++s) {
            float4 v = xg[base + s * 4];
            int igl = s >> 3, e = s & 7;
            acc[0][igl][e] = (short)bf_rne(v.x);
            acc[1][igl][e] = (short)bf_rne(v.y);
            acc[2][igl][e] = (short)bf_rne(v.z);
            acc[3][igl][e] = (short)bf_rne(v.w);
        }
        #pragma unroll
        for (int jo = 0; jo < 4; ++jo)
            #pragma unroll
            for (int igl = 0; igl < 2; ++igl) {
                int ig = ig2 * 2 + igl;
                int slot = ig ^ (pl & 3) ^ jq;
                *(bf16x8*)&xb[XB(ti, jq * 4 + jo, pl, slot)] = acc[jo][igl];
            }
        // x_s -> xsb: thread = (p, q); 2 f4 loads -> 1 ds_write_b128
        const int q = t & 7;
        const int ps = t >> 3;
        const int tis = ps >> 4, pls = ps & 15;
        const float4* xsg = (const float4*)(x_s + (size_t)p0 * 64);
        float4 v0 = xsg[ps * 16 + q * 2 + 0];
        float4 v1 = xsg[ps * 16 + q * 2 + 1];
        bf16x8 sv;
        sv[0] = (short)bf_rne(v0.x); sv[1] = (short)bf_rne(v0.y);
        sv[2] = (short)bf_rne(v0.z); sv[3] = (short)bf_rne(v0.w);
        sv[4] = (short)bf_rne(v1.x); sv[5] = (short)bf_rne(v1.y);
        sv[6] = (short)bf_rne(v1.z); sv[7] = (short)bf_rne(v1.w);
        *(bf16x8*)&xsb[((tis * 16 + pls) * 8 + (q ^ (pls & 7))) * 8] = sv;
    }

    // ---- build B fragments in registers (global f32 -> bf16; weights L2-hot) ----
    const int lane = t & 63;
    const int wid  = t >> 6;
    const int h   = wid & 1;        // o / ch half
    const int jh  = wid >> 1;       // j half
    const int col = lane & 15;
    const int g4  = lane >> 4;
    const int kb  = g4 * 8;
    const int oo  = h * 16 + col;   // global o this lane owns in B/C

    bf16x8 Bg[3], Bw[2];
    #pragma unroll
    for (int gg = 0; gg < 3; ++gg) {
        int b = 2 * jh + gg;
        #pragma unroll
        for (int e = 0; e < 8; ++e)
            Bg[gg][e] = (short)bf_rne(w_mv[oo * 288 + (kb + e) * 9 + b]);
    }
    #pragma unroll
    for (int ww = 0; ww < 2; ++ww) {
        int b = 5 + 2 * jh + ww;
        #pragma unroll
        for (int e = 0; e < 8; ++e)
            Bw[ww][e] = (short)bf_rne(w_mv[oo * 288 + (kb + e) * 9 + b]);
    }
    bf16x8 Bm2s[2], Bs2mv[2], Bs2s[2][2];
    if (jh == 0) {
        #pragma unroll
        for (int c = 0; c < 2; ++c)
            #pragma unroll
            for (int e = 0; e < 8; ++e)
                Bm2s[c][e] = (short)bf_rne(w_mv2s[((2 * h + c) * 16 + col) * 32 + kb + e]);
        #pragma unroll
        for (int kk = 0; kk < 2; ++kk) {
            #pragma unroll
            for (int e = 0; e < 8; ++e)
                Bs2mv[kk][e] = (short)bf_rne(w_s2mv[oo * 64 + kk * 32 + kb + e]);
            #pragma unroll
            for (int c = 0; c < 2; ++c)
                #pragma unroll
                for (int e = 0; e < 8; ++e)
                    Bs2s[kk][c][e] = (short)bf_rne(w_s2s[((2 * h + c) * 16 + col) * 64 + kk * 32 + kb + e]);
        }
    }

    __syncthreads();   // the ONLY barrier: xb/xsb ready

    // ---- MFMA phase ----
    f32x4 cj[2][8];
    f32x4 cs[2][2];
    #pragma unroll
    for (int ti = 0; ti < 2; ++ti) {
        #pragma unroll
        for (int jj = 0; jj < 8; ++jj) cj[ti][jj] = (f32x4){0.f, 0.f, 0.f, 0.f};
        cs[ti][0] = (f32x4){0.f, 0.f, 0.f, 0.f};
        cs[ti][1] = (f32x4){0.f, 0.f, 0.f, 0.f};
    }
    const int prow = col;

    if (jh == 0) {
        #pragma unroll
        for (int ti = 0; ti < 2; ++ti) {
            bf16x8 A0;
            #pragma unroll
            for (int jj = 0; jj < 8; ++jj) {
                int slot = g4 ^ (prow & 3) ^ (jj >> 2);
                bf16x8 A = *(const bf16x8*)&xb[XB(ti, jj, prow, slot)];
                if (jj == 0)      cj[ti][0] = MFMA(A, Bg[0], cj[ti][0]);
                else if (jj < 5)  cj[ti][jj] = MFMA(A, Bg[1], cj[ti][jj]);
                else              cj[ti][jj] = MFMA(A, Bg[2], cj[ti][jj]);
                if (jj == 0) { cj[ti][1] = MFMA(A, Bw[0], cj[ti][1]); A0 = A; }
                else if (jj == 2) cj[ti][5] = MFMA(A, Bw[1], cj[ti][5]);
                else if (jj == 3) cj[ti][6] = MFMA(A, Bw[1], cj[ti][6]);
                else if (jj == 4) cj[ti][7] = MFMA(A, Bw[1], cj[ti][7]);
            }
            cs[ti][0] = MFMA(A0, Bm2s[0], cs[ti][0]);
            cs[ti][1] = MFMA(A0, Bm2s[1], cs[ti][1]);
            #pragma unroll
            for (int kk = 0; kk < 2; ++kk) {
                const unsigned short* sp = &xsb[((ti * 16 + prow) * 8 + ((kk * 4 + g4) ^ (prow & 7))) * 8];
                bf16x8 Axs = *(const bf16x8*)sp;
                cj[ti][0] = MFMA(Axs, Bs2mv[kk], cj[ti][0]);
                cs[ti][0] = MFMA(Axs, Bs2s[kk][0], cs[ti][0]);
                cs[ti][1] = MFMA(Axs, Bs2s[kk][1], cs[ti][1]);
            }
        }
    } else {
        #pragma unroll
        for (int ti = 0; ti < 2; ++ti) {
            #pragma unroll
            for (int jj = 0; jj < 8; ++jj) {
                int j = 8 + jj;
                int slot = g4 ^ (prow & 3) ^ (j >> 2);
                bf16x8 A = *(const bf16x8*)&xb[XB(ti, j, prow, slot)];
                if (jj < 3)       cj[ti][jj] = MFMA(A, Bg[0], cj[ti][jj]);
                else if (jj < 7)  cj[ti][jj] = MFMA(A, Bg[1], cj[ti][jj]);
                else              cj[ti][jj] = MFMA(A, Bg[2], cj[ti][jj]);
                if (jj == 0)      cj[ti][3] = MFMA(A, Bw[0], cj[ti][3]);
                else if (jj == 1) cj[ti][4] = MFMA(A, Bw[0], cj[ti][4]);
                else if (jj == 2) cj[ti][5] = MFMA(A, Bw[0], cj[ti][5]);
                else if (jj == 6) cj[ti][7] = MFMA(A, Bw[1], cj[ti][7]);
            }
        }
    }

    // ---- direct epilogue: lane stores its own out float4s (no LDS, no barriers) ----
    // lane owns o = oo, parents p = ti*16 + g4*4 + r, j-quads q = jh*2 + q4.
    const float4* sk4 = (const float4*)skip_mv;
    float4* om4 = (float4*)out_mv;
    float bsv0 = 0.f, bsv1 = 0.f;
    if (jh == 0) {
        bsv0 = b_s[(2 * h + 0) * 16 + col];
        bsv1 = b_s[(2 * h + 1) * 16 + col];
    }

    #pragma unroll
    for (int ti = 0; ti < 2; ++ti) {
        #pragma unroll
        for (int r = 0; r < 4; ++r) {
            const int pg = p0 + ti * 16 + g4 * 4 + r;
            for (int cr = 0; cr < stride; ++cr) {
                const size_t cbase = ((size_t)pg * stride + cr) * 128;  // f4 units
                #pragma unroll
                for (int q4 = 0; q4 < 2; ++q4) {
                    const size_t gi = cbase + oo * 4 + (jh * 2 + q4);
                    float4 s = sk4[gi];
                    om4[gi] = make_float4(s.x + cj[ti][q4 * 4 + 0][r],
                                          s.y + cj[ti][q4 * 4 + 1][r],
                                          s.z + cj[ti][q4 * 4 + 2][r],
                                          s.w + cj[ti][q4 * 4 + 3][r]);
                }
                if (jh == 0) {
                    const size_t sbase = ((size_t)pg * stride + cr) * 64;
                    const int ch0 = (2 * h + 0) * 16 + col;
                    const int ch1 = (2 * h + 1) * 16 + col;
                    out_s[sbase + ch0] = skip_s[sbase + ch0] + cs[ti][0][r] + bsv0;
                    out_s[sbase + ch1] = skip_s[sbase + ch1] + cs[ti][1][r] + bsv1;
                }
            }
        }
    }
}

// remainder parents (n_parent % 32): slow scalar path, f32, direct global
__global__ __launch_bounds__(256) void equi_tail(
    const float* __restrict__ x_mv, const float* __restrict__ x_s,
    const float* __restrict__ skip_mv, const float* __restrict__ skip_s,
    const float* __restrict__ w_mv, const float* __restrict__ w_s2mv,
    const float* __restrict__ w_mv2s, const float* __restrict__ w_s2s,
    const float* __restrict__ b_s,
    float* __restrict__ out_mv, float* __restrict__ out_s,
    int pstart, int n_parent, int stride)
{
    int idx = blockIdx.x * blockDim.x + threadIdx.x;
    int o = idx & 31, pr = idx >> 5;
    int p = pstart + pr;
    if (p >= n_parent) return;
    float a[16];
    #pragma unroll
    for (int j = 0; j < 16; ++j) a[j] = 0.f;
    float s0 = 0.f, s1 = 0.f;
    const float4* xg = (const float4*)(x_mv + (size_t)p * 512);
    for (int i = 0; i < 32; ++i) {
        float4 X0 = xg[i * 4 + 0], X1 = xg[i * 4 + 1], X2 = xg[i * 4 + 2], X3 = xg[i * 4 + 3];
        const float* wp = &w_mv[o * 288 + i * 9];
        float w0 = wp[0], w1 = wp[1], w2 = wp[2], w3 = wp[3], w4 = wp[4];
        float w5 = wp[5], w6 = wp[6], w7 = wp[7], w8 = wp[8];
        a[0] += X0.x * w0;  a[1] += X0.y * w1 + X0.x * w5;
        a[2] += X0.z * w1;  a[3] += X0.w * w1;  a[4] += X1.x * w1;
        a[5] += X1.y * w2 + X0.z * w6;  a[6] += X1.z * w2 + X0.w * w6;
        a[7] += X1.w * w2 + X1.x * w6;  a[8] += X2.x * w2;
        a[9] += X2.y * w2;  a[10] += X2.z * w2;
        a[11] += X2.w * w3 + X2.x * w7;  a[12] += X3.x * w3 + X2.y * w7;
        a[13] += X3.y * w3 + X2.z * w7;  a[14] += X3.z * w3;
        a[15] += X3.w * w4 + X3.z * w8;
        s0 += X0.x * w_mv2s[o * 32 + i];
        s1 += X0.x * w_mv2s[(o + 32) * 32 + i];
    }
    for (int sc = 0; sc < 64; ++sc) {
        float xv = x_s[(size_t)p * 64 + sc];
        a[0] += xv * w_s2mv[o * 64 + sc];
        s0 += xv * w_s2s[o * 64 + sc];
        s1 += xv * w_s2s[(o + 32) * 64 + sc];
    }
    s0 += b_s[o]; s1 += b_s[o + 32];
    for (int r = 0; r < stride; ++r) {
        size_t c = (size_t)p * stride + r;
        const float4* sk = (const float4*)(skip_mv + c * 512 + o * 16);
        float4* om = (float4*)(out_mv + c * 512 + o * 16);
        float4 k0 = sk[0], k1 = sk[1], k2 = sk[2], k3 = sk[3];
        om[0] = make_float4(k0.x + a[0],  k0.y + a[1],  k0.z + a[2],  k0.w + a[3]);
        om[1] = make_float4(k1.x + a[4],  k1.y + a[5],  k1.z + a[6],  k1.w + a[7]);
        om[2] = make_float4(k2.x + a[8],  k2.y + a[9],  k2.z + a[10], k2.w + a[11]);
        om[3] = make_float4(k3.x + a[12], k3.y + a[13], k3.z + a[14], k3.w + a[15]);
        out_s[c * 64 + o]      = skip_s[c * 64 + o] + s0;
        out_s[c * 64 + o + 32] = skip_s[c * 64 + o + 32] + s1;
    }
}

extern "C" void kernel_launch(void* const* d_in, const int* in_sizes, int n_in,
                              void* d_out, int out_size, void* d_ws, size_t ws_size,
                              hipStream_t stream) {
    const float* x_mv    = (const float*)d_in[0];
    const float* x_s     = (const float*)d_in[1];
    const float* skip_mv = (const float*)d_in[2];
    const float* skip_s  = (const float*)d_in[3];
    const float* w_mv    = (const float*)d_in[4];
    const float* w_s2mv  = (const float*)d_in[5];
    const float* w_mv2s  = (const float*)d_in[6];
    const float* w_s2s   = (const float*)d_in[7];
    const float* b_s     = (const float*)d_in[8];

    const int n_parent = in_sizes[0] / 512;
    const int n_child  = in_sizes[2] / 512;
    const int stride   = n_child / n_parent;

    float* out_mv = (float*)d_out;
    float* out_s  = out_mv + (size_t)n_child * 512;

    const int full = n_parent >> 5;
    const int rem  = n_parent & 31;
    if (full > 0)
        equi_mfma<<<full, THR, 0, stream>>>(
            x_mv, x_s, skip_mv, skip_s, w_mv, w_s2mv, w_mv2s, w_s2s, b_s,
            out_mv, out_s, n_parent, stride);
    if (rem > 0) {
        int thr = rem * 32;
        int blk = (thr + 255) / 256;
        equi_tail<<<blk, 256, 0, stream>>>(
            x_mv, x_s, skip_mv, skip_s, w_mv, w_s2mv, w_mv2s, w_s2s, b_s,
            out_mv, out_s, full * 32, n_parent, stride);
    }
}

// Round 14
// 177.251 us; speedup vs baseline: 1.3846x; 1.3846x over previous
//
#include <hip/hip_runtime.h>

typedef __attribute__((ext_vector_type(8))) short bf16x8;
typedef __attribute__((ext_vector_type(4))) float f32x4;

#define THR 256
#define PBLK 32

__device__ __forceinline__ unsigned int bf_rne(float f) {
    unsigned int u = __float_as_uint(f);
    u += 0x7fffu + ((u >> 16) & 1u);
    return u >> 16;
}

__device__ __forceinline__ void nt_store4(float4* p, float4 v) {
    __builtin_nontemporal_store(v.x, &p->x);
    __builtin_nontemporal_store(v.y, &p->y);
    __builtin_nontemporal_store(v.z, &p->z);
    __builtin_nontemporal_store(v.w, &p->w);
}

#define MFMA(A, B, C) __builtin_amdgcn_mfma_f32_16x16x32_bf16((A), (B), (C), 0, 0, 0)

// xb u16 index: j-stride 520, slot XOR'd with ig/pl/jq (A-reads/writes ~2-way)
#define XB(ti, j, pl, slot) ((ti) * 8320 + (j) * 520 + (pl) * 32 + (slot) * 8)
#define YPS 520   // y p-stride (f32): 32 o x 16 j + 8 pad
#define YSS 68    // ys p-stride (f32): 64 ch + 4 pad

__global__ __launch_bounds__(THR) void equi_mfma(
    const float* __restrict__ x_mv,    // [Np,32,16]
    const float* __restrict__ x_s,     // [Np,64]
    const float* __restrict__ skip_mv, // [Nc,32,16]
    const float* __restrict__ skip_s,  // [Nc,64]
    const float* __restrict__ w_mv,    // [32,32,9]
    const float* __restrict__ w_s2mv,  // [32,64]
    const float* __restrict__ w_mv2s,  // [64,32]
    const float* __restrict__ w_s2s,   // [64,64]
    const float* __restrict__ b_s,     // [64]
    float* __restrict__ out_mv,        // [Nc,32,16]
    float* __restrict__ out_s,         // [Nc,64]
    int n_parent, int stride)
{
    // Union LDS. staging view: xb 33280 B + xsb 4096 B = 37376 B.
    // epilogue view: y 16p*520*4 = 33280 B (over xb) + ys 16p*68*4 = 4352 B = 37632 B.
    __shared__ char smem[37632];
    unsigned short* xb  = (unsigned short*)smem;
    unsigned short* xsb = (unsigned short*)(smem + 33280);
    float* y  = (float*)smem;                       // Y(p,o,quad',m) = p*520 + o*16 + quad'*4 + m
    float* ys = (float*)(smem + 33280);             // YS(p,ch) = p*68 + ch

    const int t  = threadIdx.x;
    const int p0 = blockIdx.x * PBLK;

    // ---- stage x_mv -> xb: thread = (p, ig2, jq); 16 f4 loads -> 8 ds_write_b128 ----
    {
        const int p   = t >> 3;
        const int ig2 = (t >> 2) & 1;
        const int jq  = t & 3;
        const int ti  = p >> 4, pl = p & 15;
        const float4* xg = (const float4*)(x_mv + (size_t)p0 * 512);
        const int base = p * 128 + ig2 * 64 + jq;
        bf16x8 acc[4][2];     // [jo][igl]
        #pragma unroll
        for (int s = 0; s < 16; ++s) {
            float4 v = xg[base + s * 4];
            int igl = s >> 3, e = s & 7;
            acc[0][igl][e] = (short)bf_rne(v.x);
            acc[1][igl][e] = (short)bf_rne(v.y);
            acc[2][igl][e] = (short)bf_rne(v.z);
            acc[3][igl][e] = (short)bf_rne(v.w);
        }
        #pragma unroll
        for (int jo = 0; jo < 4; ++jo)
            #pragma unroll
            for (int igl = 0; igl < 2; ++igl) {
                int ig = ig2 * 2 + igl;
                int slot = ig ^ (pl & 3) ^ jq;
                *(bf16x8*)&xb[XB(ti, jq * 4 + jo, pl, slot)] = acc[jo][igl];
            }
        // x_s -> xsb: thread = (p, q); 2 f4 loads -> 1 ds_write_b128
        const int q = t & 7;
        const int ps = t >> 3;
        const int tis = ps >> 4, pls = ps & 15;
        const float4* xsg = (const float4*)(x_s + (size_t)p0 * 64);
        float4 v0 = xsg[ps * 16 + q * 2 + 0];
        float4 v1 = xsg[ps * 16 + q * 2 + 1];
        bf16x8 sv;
        sv[0] = (short)bf_rne(v0.x); sv[1] = (short)bf_rne(v0.y);
        sv[2] = (short)bf_rne(v0.z); sv[3] = (short)bf_rne(v0.w);
        sv[4] = (short)bf_rne(v1.x); sv[5] = (short)bf_rne(v1.y);
        sv[6] = (short)bf_rne(v1.z); sv[7] = (short)bf_rne(v1.w);
        *(bf16x8*)&xsb[((tis * 16 + pls) * 8 + (q ^ (pls & 7))) * 8] = sv;
    }

    // ---- build B fragments in registers (global f32 -> bf16; weights L2-hot) ----
    const int lane = t & 63;
    const int wid  = t >> 6;
    const int h   = wid & 1;        // o / ch half
    const int jh  = wid >> 1;       // j half
    const int col = lane & 15;
    const int g4  = lane >> 4;
    const int kb  = g4 * 8;
    const int oo  = h * 16 + col;   // global o this lane owns in B/C

    bf16x8 Bg[3], Bw[2];
    #pragma unroll
    for (int gg = 0; gg < 3; ++gg) {
        int b = 2 * jh + gg;
        #pragma unroll
        for (int e = 0; e < 8; ++e)
            Bg[gg][e] = (short)bf_rne(w_mv[oo * 288 + (kb + e) * 9 + b]);
    }
    #pragma unroll
    for (int ww = 0; ww < 2; ++ww) {
        int b = 5 + 2 * jh + ww;
        #pragma unroll
        for (int e = 0; e < 8; ++e)
            Bw[ww][e] = (short)bf_rne(w_mv[oo * 288 + (kb + e) * 9 + b]);
    }
    bf16x8 Bm2s[2], Bs2mv[2], Bs2s[2][2];
    if (jh == 0) {
        #pragma unroll
        for (int c = 0; c < 2; ++c)
            #pragma unroll
            for (int e = 0; e < 8; ++e)
                Bm2s[c][e] = (short)bf_rne(w_mv2s[((2 * h + c) * 16 + col) * 32 + kb + e]);
        #pragma unroll
        for (int kk = 0; kk < 2; ++kk) {
            #pragma unroll
            for (int e = 0; e < 8; ++e)
                Bs2mv[kk][e] = (short)bf_rne(w_s2mv[oo * 64 + kk * 32 + kb + e]);
            #pragma unroll
            for (int c = 0; c < 2; ++c)
                #pragma unroll
                for (int e = 0; e < 8; ++e)
                    Bs2s[kk][c][e] = (short)bf_rne(w_s2s[((2 * h + c) * 16 + col) * 64 + kk * 32 + kb + e]);
        }
    }

    __syncthreads();   // barrier #1: xb/xsb ready

    // ---- MFMA phase ----
    f32x4 cj[2][8];
    f32x4 cs[2][2];
    #pragma unroll
    for (int ti = 0; ti < 2; ++ti) {
        #pragma unroll
        for (int jj = 0; jj < 8; ++jj) cj[ti][jj] = (f32x4){0.f, 0.f, 0.f, 0.f};
        cs[ti][0] = (f32x4){0.f, 0.f, 0.f, 0.f};
        cs[ti][1] = (f32x4){0.f, 0.f, 0.f, 0.f};
    }
    const int prow = col;

    if (jh == 0) {
        #pragma unroll
        for (int ti = 0; ti < 2; ++ti) {
            bf16x8 A0;
            #pragma unroll
            for (int jj = 0; jj < 8; ++jj) {
                int slot = g4 ^ (prow & 3) ^ (jj >> 2);
                bf16x8 A = *(const bf16x8*)&xb[XB(ti, jj, prow, slot)];
                if (jj == 0)      cj[ti][0] = MFMA(A, Bg[0], cj[ti][0]);
                else if (jj < 5)  cj[ti][jj] = MFMA(A, Bg[1], cj[ti][jj]);
                else              cj[ti][jj] = MFMA(A, Bg[2], cj[ti][jj]);
                if (jj == 0) { cj[ti][1] = MFMA(A, Bw[0], cj[ti][1]); A0 = A; }
                else if (jj == 2) cj[ti][5] = MFMA(A, Bw[1], cj[ti][5]);
                else if (jj == 3) cj[ti][6] = MFMA(A, Bw[1], cj[ti][6]);
                else if (jj == 4) cj[ti][7] = MFMA(A, Bw[1], cj[ti][7]);
            }
            cs[ti][0] = MFMA(A0, Bm2s[0], cs[ti][0]);
            cs[ti][1] = MFMA(A0, Bm2s[1], cs[ti][1]);
            #pragma unroll
            for (int kk = 0; kk < 2; ++kk) {
                const unsigned short* sp = &xsb[((ti * 16 + prow) * 8 + ((kk * 4 + g4) ^ (prow & 7))) * 8];
                bf16x8 Axs = *(const bf16x8*)sp;
                cj[ti][0] = MFMA(Axs, Bs2mv[kk], cj[ti][0]);
                cs[ti][0] = MFMA(Axs, Bs2s[kk][0], cs[ti][0]);
                cs[ti][1] = MFMA(Axs, Bs2s[kk][1], cs[ti][1]);
            }
        }
    } else {
        #pragma unroll
        for (int ti = 0; ti < 2; ++ti) {
            #pragma unroll
            for (int jj = 0; jj < 8; ++jj) {
                int j = 8 + jj;
                int slot = g4 ^ (prow & 3) ^ (j >> 2);
                bf16x8 A = *(const bf16x8*)&xb[XB(ti, j, prow, slot)];
                if (jj < 3)       cj[ti][jj] = MFMA(A, Bg[0], cj[ti][jj]);
                else if (jj < 7)  cj[ti][jj] = MFMA(A, Bg[1], cj[ti][jj]);
                else              cj[ti][jj] = MFMA(A, Bg[2], cj[ti][jj]);
                if (jj == 0)      cj[ti][3] = MFMA(A, Bw[0], cj[ti][3]);
                else if (jj == 1) cj[ti][4] = MFMA(A, Bw[0], cj[ti][4]);
                else if (jj == 2) cj[ti][5] = MFMA(A, Bw[0], cj[ti][5]);
                else if (jj == 6) cj[ti][7] = MFMA(A, Bw[1], cj[ti][7]);
            }
        }
    }

    // ---- epilogue: 2 half-tiles of 16 parents; vectorized C->y then coalesced nt stream ----
    #pragma unroll
    for (int hf = 0; hf < 2; ++hf) {
        __syncthreads();   // xb/xsb dead (hf=0) / prev y-reads done (hf=1)
        #pragma unroll
        for (int r = 0; r < 4; ++r) {
            int p = g4 * 4 + r;
            #pragma unroll
            for (int q4 = 0; q4 < 2; ++q4) {
                int jqg  = jh * 2 + q4;                 // global j-quad
                int quad = jqg ^ (oo & 3) ^ g4;         // g4 == p>>2
                float4 w;
                w.x = cj[hf][q4 * 4 + 0][r];
                w.y = cj[hf][q4 * 4 + 1][r];
                w.z = cj[hf][q4 * 4 + 2][r];
                w.w = cj[hf][q4 * 4 + 3][r];
                *(float4*)&y[p * YPS + oo * 16 + quad * 4] = w;
            }
        }
        if (jh == 0) {
            #pragma unroll
            for (int c = 0; c < 2; ++c)
                #pragma unroll
                for (int r = 0; r < 4; ++r)
                    ys[(g4 * 4 + r) * YSS + (2 * h + c) * 16 + col] = cs[hf][c][r];
        }
        __syncthreads();   // y ready

        const int cbase = (p0 + hf * 16) * stride;
        const float4* sk4 = (const float4*)skip_mv;
        float4* om4 = (float4*)out_mv;
        const float4* sks4 = (const float4*)skip_s;
        float4* os4 = (float4*)out_s;
        const float4* bs4 = (const float4*)b_s;

        if (stride == 2) {
            const int totmv = 16 * 2 * 128;        // 4096 f4
            for (int id = t; id < totmv; id += THR) {
                int child = id >> 7, rem = id & 127;
                int o = rem >> 2, q = rem & 3;
                int ph = child >> 1;
                int quad = q ^ (o & 3) ^ (ph >> 2);
                float4 ad = *(const float4*)&y[ph * YPS + o * 16 + quad * 4];
                size_t gi = (size_t)(cbase + child) * 128 + rem;
                float4 s = sk4[gi];
                nt_store4(&om4[gi], make_float4(s.x + ad.x, s.y + ad.y, s.z + ad.z, s.w + ad.w));
            }
            const int tots = 16 * 2 * 16;          // 512 f4
            for (int id = t; id < tots; id += THR) {
                int child = id >> 4, ch4 = id & 15;
                int ph = child >> 1;
                float4 ad = *(const float4*)&ys[ph * YSS + ch4 * 4];
                float4 bb = bs4[ch4];
                size_t gi = (size_t)(cbase + child) * 16 + ch4;
                float4 s = sks4[gi];
                nt_store4(&os4[gi], make_float4(s.x + ad.x + bb.x, s.y + ad.y + bb.y,
                                                s.z + ad.z + bb.z, s.w + ad.w + bb.w));
            }
        } else {
            const int totmv = 16 * stride * 128;
            for (int id = t; id < totmv; id += THR) {
                int child = id >> 7, rem = id & 127;
                int o = rem >> 2, q = rem & 3;
                int ph = child / stride;
                int quad = q ^ (o & 3) ^ (ph >> 2);
                float4 ad = *(const float4*)&y[ph * YPS + o * 16 + quad * 4];
                size_t gi = (size_t)(cbase + child) * 128 + rem;
                float4 s = sk4[gi];
                nt_store4(&om4[gi], make_float4(s.x + ad.x, s.y + ad.y, s.z + ad.z, s.w + ad.w));
            }
            const int tots = 16 * stride * 16;
            for (int id = t; id < tots; id += THR) {
                int child = id >> 4, ch4 = id & 15;
                int ph = child / stride;
                float4 ad = *(const float4*)&ys[ph * YSS + ch4 * 4];
                float4 bb = bs4[ch4];
                size_t gi = (size_t)(cbase + child) * 16 + ch4;
                float4 s = sks4[gi];
                nt_store4(&os4[gi], make_float4(s.x + ad.x + bb.x, s.y + ad.y + bb.y,
                                                s.z + ad.z + bb.z, s.w + ad.w + bb.w));
            }
        }
    }
}

// remainder parents (n_parent % 32): slow scalar path, f32, direct global
__global__ __launch_bounds__(256) void equi_tail(
    const float* __restrict__ x_mv, const float* __restrict__ x_s,
    const float* __restrict__ skip_mv, const float* __restrict__ skip_s,
    const float* __restrict__ w_mv, const float* __restrict__ w_s2mv,
    const float* __restrict__ w_mv2s, const float* __restrict__ w_s2s,
    const float* __restrict__ b_s,
    float* __restrict__ out_mv, float* __restrict__ out_s,
    int pstart, int n_parent, int stride)
{
    int idx = blockIdx.x * blockDim.x + threadIdx.x;
    int o = idx & 31, pr = idx >> 5;
    int p = pstart + pr;
    if (p >= n_parent) return;
    float a[16];
    #pragma unroll
    for (int j = 0; j < 16; ++j) a[j] = 0.f;
    float s0 = 0.f, s1 = 0.f;
    const float4* xg = (const float4*)(x_mv + (size_t)p * 512);
    for (int i = 0; i < 32; ++i) {
        float4 X0 = xg[i * 4 + 0], X1 = xg[i * 4 + 1], X2 = xg[i * 4 + 2], X3 = xg[i * 4 + 3];
        const float* wp = &w_mv[o * 288 + i * 9];
        float w0 = wp[0], w1 = wp[1], w2 = wp[2], w3 = wp[3], w4 = wp[4];
        float w5 = wp[5], w6 = wp[6], w7 = wp[7], w8 = wp[8];
        a[0] += X0.x * w0;  a[1] += X0.y * w1 + X0.x * w5;
        a[2] += X0.z * w1;  a[3] += X0.w * w1;  a[4] += X1.x * w1;
        a[5] += X1.y * w2 + X0.z * w6;  a[6] += X1.z * w2 + X0.w * w6;
        a[7] += X1.w * w2 + X1.x * w6;  a[8] += X2.x * w2;
        a[9] += X2.y * w2;  a[10] += X2.z * w2;
        a[11] += X2.w * w3 + X2.x * w7;  a[12] += X3.x * w3 + X2.y * w7;
        a[13] += X3.y * w3 + X2.z * w7;  a[14] += X3.z * w3;
        a[15] += X3.w * w4 + X3.z * w8;
        s0 += X0.x * w_mv2s[o * 32 + i];
        s1 += X0.x * w_mv2s[(o + 32) * 32 + i];
    }
    for (int sc = 0; sc < 64; ++sc) {
        float xv = x_s[(size_t)p * 64 + sc];
        a[0] += xv * w_s2mv[o * 64 + sc];
        s0 += xv * w_s2s[o * 64 + sc];
        s1 += xv * w_s2s[(o + 32) * 64 + sc];
    }
    s0 += b_s[o]; s1 += b_s[o + 32];
    for (int r = 0; r < stride; ++r) {
        size_t c = (size_t)p * stride + r;
        const float4* sk = (const float4*)(skip_mv + c * 512 + o * 16);
        float4* om = (float4*)(out_mv + c * 512 + o * 16);
        float4 k0 = sk[0], k1 = sk[1], k2 = sk[2], k3 = sk[3];
        om[0] = make_float4(k0.x + a[0],  k0.y + a[1],  k0.z + a[2],  k0.w + a[3]);
        om[1] = make_float4(k1.x + a[4],  k1.y + a[5],  k1.z + a[6],  k1.w + a[7]);
        om[2] = make_float4(k2.x + a[8],  k2.y + a[9],  k2.z + a[10], k2.w + a[11]);
        om[3] = make_float4(k3.x + a[12], k3.y + a[13], k3.z + a[14], k3.w + a[15]);
        out_s[c * 64 + o]      = skip_s[c * 64 + o] + s0;
        out_s[c * 64 + o + 32] = skip_s[c * 64 + o + 32] + s1;
    }
}

extern "C" void kernel_launch(void* const* d_in, const int* in_sizes, int n_in,
                              void* d_out, int out_size, void* d_ws, size_t ws_size,
                              hipStream_t stream) {
    const float* x_mv    = (const float*)d_in[0];
    const float* x_s     = (const float*)d_in[1];
    const float* skip_mv = (const float*)d_in[2];
    const float* skip_s  = (const float*)d_in[3];
    const float* w_mv    = (const float*)d_in[4];
    const float* w_s2mv  = (const float*)d_in[5];
    const float* w_mv2s  = (const float*)d_in[6];
    const float* w_s2s   = (const float*)d_in[7];
    const float* b_s     = (const float*)d_in[8];

    const int n_parent = in_sizes[0] / 512;
    const int n_child  = in_sizes[2] / 512;
    const int stride   = n_child / n_parent;

    float* out_mv = (float*)d_out;
    float* out_s  = out_mv + (size_t)n_child * 512;

    const int full = n_parent >> 5;
    const int rem  = n_parent & 31;
    if (full > 0)
        equi_mfma<<<full, THR, 0, stream>>>(
            x_mv, x_s, skip_mv, skip_s, w_mv, w_s2mv, w_mv2s, w_s2s, b_s,
            out_mv, out_s, n_parent, stride);
    if (rem > 0) {
        int thr = rem * 32;
        int blk = (thr + 255) / 256;
        equi_tail<<<blk, 256, 0, stream>>>(
            x_mv, x_s, skip_mv, skip_s, w_mv, w_s2mv, w_mv2s, w_s2s, b_s,
            out_mv, out_s, full * 32, n_parent, stride);
    }
}

// Round 15
// 161.299 us; speedup vs baseline: 1.5216x; 1.0989x over previous
//
#include <hip/hip_runtime.h>

typedef __attribute__((ext_vector_type(8))) short bf16x8;
typedef __attribute__((ext_vector_type(4))) float f32x4;

#define THR 256
#define PBLK 32

__device__ __forceinline__ unsigned int bf_rne(float f) {
    unsigned int u = __float_as_uint(f);
    u += 0x7fffu + ((u >> 16) & 1u);
    return u >> 16;
}

#define MFMA(A, B, C) __builtin_amdgcn_mfma_f32_16x16x32_bf16((A), (B), (C), 0, 0, 0)

// xb u16 index: j-stride 520, slot XOR'd with ig/pl/jq (A-reads/writes ~2-way)
#define XB(ti, j, pl, slot) ((ti) * 8320 + (j) * 520 + (pl) * 32 + (slot) * 8)
#define YPS 520   // y p-stride (f32): 32 o x 16 j + 8 pad
#define YSS 68    // ys p-stride (f32): 64 ch + 4 pad

// ws fragment slots: 0-2 Bg, 3-4 Bw, 5-6 Bm2s, 7-8 Bs2mv, 9-12 Bs2s  -> 13 x 16B x 256 thr
#define NSLOT 13

// ---- one-block init: build per-thread B fragments once, store [slot][tid] ----
__global__ __launch_bounds__(THR) void build_frags(
    const float* __restrict__ w_mv, const float* __restrict__ w_s2mv,
    const float* __restrict__ w_mv2s, const float* __restrict__ w_s2s,
    bf16x8* __restrict__ wsf)
{
    const int t = threadIdx.x;
    const int lane = t & 63;
    const int wid  = t >> 6;
    const int h   = wid & 1;
    const int jh  = wid >> 1;
    const int col = lane & 15;
    const int g4  = lane >> 4;
    const int kb  = g4 * 8;
    const int oo  = h * 16 + col;

    bf16x8 z;
    #pragma unroll
    for (int e = 0; e < 8; ++e) z[e] = 0;

    #pragma unroll
    for (int gg = 0; gg < 3; ++gg) {
        int b = 2 * jh + gg;
        bf16x8 v = z;
        #pragma unroll
        for (int e = 0; e < 8; ++e)
            v[e] = (short)bf_rne(w_mv[oo * 288 + (kb + e) * 9 + b]);
        wsf[gg * THR + t] = v;
    }
    #pragma unroll
    for (int ww = 0; ww < 2; ++ww) {
        int b = 5 + 2 * jh + ww;
        bf16x8 v = z;
        #pragma unroll
        for (int e = 0; e < 8; ++e)
            v[e] = (short)bf_rne(w_mv[oo * 288 + (kb + e) * 9 + b]);
        wsf[(3 + ww) * THR + t] = v;
    }
    if (jh == 0) {
        #pragma unroll
        for (int c = 0; c < 2; ++c) {
            bf16x8 v = z;
            #pragma unroll
            for (int e = 0; e < 8; ++e)
                v[e] = (short)bf_rne(w_mv2s[((2 * h + c) * 16 + col) * 32 + kb + e]);
            wsf[(5 + c) * THR + t] = v;
        }
        #pragma unroll
        for (int kk = 0; kk < 2; ++kk) {
            bf16x8 v = z;
            #pragma unroll
            for (int e = 0; e < 8; ++e)
                v[e] = (short)bf_rne(w_s2mv[oo * 64 + kk * 32 + kb + e]);
            wsf[(7 + kk) * THR + t] = v;
            #pragma unroll
            for (int c = 0; c < 2; ++c) {
                bf16x8 u = z;
                #pragma unroll
                for (int e = 0; e < 8; ++e)
                    u[e] = (short)bf_rne(w_s2s[((2 * h + c) * 16 + col) * 64 + kk * 32 + kb + e]);
                wsf[(9 + kk * 2 + c) * THR + t] = u;
            }
        }
    } else {
        #pragma unroll
        for (int s = 5; s < NSLOT; ++s) wsf[s * THR + t] = z;
    }
}

__global__ __launch_bounds__(THR) void equi_mfma(
    const float* __restrict__ x_mv,    // [Np,32,16]
    const float* __restrict__ x_s,     // [Np,64]
    const float* __restrict__ skip_mv, // [Nc,32,16]
    const float* __restrict__ skip_s,  // [Nc,64]
    const bf16x8* __restrict__ wsf,    // [13][256] precomputed B fragments
    const float* __restrict__ b_s,     // [64]
    float* __restrict__ out_mv,        // [Nc,32,16]
    float* __restrict__ out_s,         // [Nc,64]
    int n_parent, int stride)
{
    // Union LDS. staging view: xb 33280 B + xsb 4096 B = 37376 B.
    // epilogue view: y 16p*520*4 = 33280 B (over xb) + ys 16p*68*4 = 4352 B = 37632 B.
    __shared__ char smem[37632];
    unsigned short* xb  = (unsigned short*)smem;
    unsigned short* xsb = (unsigned short*)(smem + 33280);
    float* y  = (float*)smem;                       // Y(p,o,quad',m) = p*520 + o*16 + quad'*4 + m
    float* ys = (float*)(smem + 33280);             // YS(p,ch) = p*68 + ch

    const int t  = threadIdx.x;
    const int p0 = blockIdx.x * PBLK;

    // ---- stage x_mv -> xb: thread = (p, ig2, jq); 16 f4 loads -> 8 ds_write_b128 ----
    {
        const int p   = t >> 3;
        const int ig2 = (t >> 2) & 1;
        const int jq  = t & 3;
        const int ti  = p >> 4, pl = p & 15;
        const float4* xg = (const float4*)(x_mv + (size_t)p0 * 512);
        const int base = p * 128 + ig2 * 64 + jq;
        bf16x8 acc[4][2];     // [jo][igl]
        #pragma unroll
        for (int s = 0; s < 16; ++s) {
            float4 v = xg[base + s * 4];
            int igl = s >> 3, e = s & 7;
            acc[0][igl][e] = (short)bf_rne(v.x);
            acc[1][igl][e] = (short)bf_rne(v.y);
            acc[2][igl][e] = (short)bf_rne(v.z);
            acc[3][igl][e] = (short)bf_rne(v.w);
        }
        #pragma unroll
        for (int jo = 0; jo < 4; ++jo)
            #pragma unroll
            for (int igl = 0; igl < 2; ++igl) {
                int ig = ig2 * 2 + igl;
                int slot = ig ^ (pl & 3) ^ jq;
                *(bf16x8*)&xb[XB(ti, jq * 4 + jo, pl, slot)] = acc[jo][igl];
            }
        // x_s -> xsb: thread = (p, q); 2 f4 loads -> 1 ds_write_b128
        const int q = t & 7;
        const int ps = t >> 3;
        const int tis = ps >> 4, pls = ps & 15;
        const float4* xsg = (const float4*)(x_s + (size_t)p0 * 64);
        float4 v0 = xsg[ps * 16 + q * 2 + 0];
        float4 v1 = xsg[ps * 16 + q * 2 + 1];
        bf16x8 sv;
        sv[0] = (short)bf_rne(v0.x); sv[1] = (short)bf_rne(v0.y);
        sv[2] = (short)bf_rne(v0.z); sv[3] = (short)bf_rne(v0.w);
        sv[4] = (short)bf_rne(v1.x); sv[5] = (short)bf_rne(v1.y);
        sv[6] = (short)bf_rne(v1.z); sv[7] = (short)bf_rne(v1.w);
        *(bf16x8*)&xsb[((tis * 16 + pls) * 8 + (q ^ (pls & 7))) * 8] = sv;
    }

    // ---- load precomputed B fragments: 13 coalesced dwordx4 (L2-hot) ----
    const int lane = t & 63;
    const int wid  = t >> 6;
    const int h   = wid & 1;
    const int jh  = wid >> 1;
    const int col = lane & 15;
    const int g4  = lane >> 4;
    const int oo  = h * 16 + col;

    bf16x8 Bg[3], Bw[2], Bm2s[2], Bs2mv[2], Bs2s[2][2];
    Bg[0]      = wsf[0 * THR + t];
    Bg[1]      = wsf[1 * THR + t];
    Bg[2]      = wsf[2 * THR + t];
    Bw[0]      = wsf[3 * THR + t];
    Bw[1]      = wsf[4 * THR + t];
    Bm2s[0]    = wsf[5 * THR + t];
    Bm2s[1]    = wsf[6 * THR + t];
    Bs2mv[0]   = wsf[7 * THR + t];
    Bs2mv[1]   = wsf[8 * THR + t];
    Bs2s[0][0] = wsf[9 * THR + t];
    Bs2s[0][1] = wsf[10 * THR + t];
    Bs2s[1][0] = wsf[11 * THR + t];
    Bs2s[1][1] = wsf[12 * THR + t];

    __syncthreads();   // barrier #1: xb/xsb ready

    // ---- MFMA phase ----
    f32x4 cj[2][8];
    f32x4 cs[2][2];
    #pragma unroll
    for (int ti = 0; ti < 2; ++ti) {
        #pragma unroll
        for (int jj = 0; jj < 8; ++jj) cj[ti][jj] = (f32x4){0.f, 0.f, 0.f, 0.f};
        cs[ti][0] = (f32x4){0.f, 0.f, 0.f, 0.f};
        cs[ti][1] = (f32x4){0.f, 0.f, 0.f, 0.f};
    }
    const int prow = col;

    if (jh == 0) {
        #pragma unroll
        for (int ti = 0; ti < 2; ++ti) {
            bf16x8 A0;
            #pragma unroll
            for (int jj = 0; jj < 8; ++jj) {
                int slot = g4 ^ (prow & 3) ^ (jj >> 2);
                bf16x8 A = *(const bf16x8*)&xb[XB(ti, jj, prow, slot)];
                if (jj == 0)      cj[ti][0] = MFMA(A, Bg[0], cj[ti][0]);
                else if (jj < 5)  cj[ti][jj] = MFMA(A, Bg[1], cj[ti][jj]);
                else              cj[ti][jj] = MFMA(A, Bg[2], cj[ti][jj]);
                if (jj == 0) { cj[ti][1] = MFMA(A, Bw[0], cj[ti][1]); A0 = A; }
                else if (jj == 2) cj[ti][5] = MFMA(A, Bw[1], cj[ti][5]);
                else if (jj == 3) cj[ti][6] = MFMA(A, Bw[1], cj[ti][6]);
                else if (jj == 4) cj[ti][7] = MFMA(A, Bw[1], cj[ti][7]);
            }
            cs[ti][0] = MFMA(A0, Bm2s[0], cs[ti][0]);
            cs[ti][1] = MFMA(A0, Bm2s[1], cs[ti][1]);
            #pragma unroll
            for (int kk = 0; kk < 2; ++kk) {
                const unsigned short* sp = &xsb[((ti * 16 + prow) * 8 + ((kk * 4 + g4) ^ (prow & 7))) * 8];
                bf16x8 Axs = *(const bf16x8*)sp;
                cj[ti][0] = MFMA(Axs, Bs2mv[kk], cj[ti][0]);
                cs[ti][0] = MFMA(Axs, Bs2s[kk][0], cs[ti][0]);
                cs[ti][1] = MFMA(Axs, Bs2s[kk][1], cs[ti][1]);
            }
        }
    } else {
        #pragma unroll
        for (int ti = 0; ti < 2; ++ti) {
            #pragma unroll
            for (int jj = 0; jj < 8; ++jj) {
                int j = 8 + jj;
                int slot = g4 ^ (prow & 3) ^ (j >> 2);
                bf16x8 A = *(const bf16x8*)&xb[XB(ti, j, prow, slot)];
                if (jj < 3)       cj[ti][jj] = MFMA(A, Bg[0], cj[ti][jj]);
                else if (jj < 7)  cj[ti][jj] = MFMA(A, Bg[1], cj[ti][jj]);
                else              cj[ti][jj] = MFMA(A, Bg[2], cj[ti][jj]);
                if (jj == 0)      cj[ti][3] = MFMA(A, Bw[0], cj[ti][3]);
                else if (jj == 1) cj[ti][4] = MFMA(A, Bw[0], cj[ti][4]);
                else if (jj == 2) cj[ti][5] = MFMA(A, Bw[0], cj[ti][5]);
                else if (jj == 6) cj[ti][7] = MFMA(A, Bw[1], cj[ti][7]);
            }
        }
    }

    // ---- epilogue: 2 half-tiles of 16 parents; vectorized C->y then coalesced stream ----
    #pragma unroll
    for (int hf = 0; hf < 2; ++hf) {
        __syncthreads();   // xb/xsb dead (hf=0) / prev y-reads done (hf=1)
        #pragma unroll
        for (int r = 0; r < 4; ++r) {
            int p = g4 * 4 + r;
            #pragma unroll
            for (int q4 = 0; q4 < 2; ++q4) {
                int jqg  = jh * 2 + q4;                 // global j-quad
                int quad = jqg ^ (oo & 3) ^ g4;         // g4 == p>>2
                float4 w;
                w.x = cj[hf][q4 * 4 + 0][r];
                w.y = cj[hf][q4 * 4 + 1][r];
                w.z = cj[hf][q4 * 4 + 2][r];
                w.w = cj[hf][q4 * 4 + 3][r];
                *(float4*)&y[p * YPS + oo * 16 + quad * 4] = w;
            }
        }
        if (jh == 0) {
            #pragma unroll
            for (int c = 0; c < 2; ++c)
                #pragma unroll
                for (int r = 0; r < 4; ++r)
                    ys[(g4 * 4 + r) * YSS + (2 * h + c) * 16 + col] = cs[hf][c][r];
        }
        __syncthreads();   // y ready

        const int cbase = (p0 + hf * 16) * stride;
        const float4* sk4 = (const float4*)skip_mv;
        float4* om4 = (float4*)out_mv;
        const float4* sks4 = (const float4*)skip_s;
        float4* os4 = (float4*)out_s;
        const float4* bs4 = (const float4*)b_s;

        if (stride == 2) {
            const int totmv = 16 * 2 * 128;        // 4096 f4
            for (int id = t; id < totmv; id += THR) {
                int child = id >> 7, rem = id & 127;
                int o = rem >> 2, q = rem & 3;
                int ph = child >> 1;
                int quad = q ^ (o & 3) ^ (ph >> 2);
                float4 ad = *(const float4*)&y[ph * YPS + o * 16 + quad * 4];
                size_t gi = (size_t)(cbase + child) * 128 + rem;
                float4 s = sk4[gi];
                om4[gi] = make_float4(s.x + ad.x, s.y + ad.y, s.z + ad.z, s.w + ad.w);
            }
            const int tots = 16 * 2 * 16;          // 512 f4
            for (int id = t; id < tots; id += THR) {
                int child = id >> 4, ch4 = id & 15;
                int ph = child >> 1;
                float4 ad = *(const float4*)&ys[ph * YSS + ch4 * 4];
                float4 bb = bs4[ch4];
                size_t gi = (size_t)(cbase + child) * 16 + ch4;
                float4 s = sks4[gi];
                os4[gi] = make_float4(s.x + ad.x + bb.x, s.y + ad.y + bb.y,
                                      s.z + ad.z + bb.z, s.w + ad.w + bb.w);
            }
        } else {
            const int totmv = 16 * stride * 128;
            for (int id = t; id < totmv; id += THR) {
                int child = id >> 7, rem = id & 127;
                int o = rem >> 2, q = rem & 3;
                int ph = child / stride;
                int quad = q ^ (o & 3) ^ (ph >> 2);
                float4 ad = *(const float4*)&y[ph * YPS + o * 16 + quad * 4];
                size_t gi = (size_t)(cbase + child) * 128 + rem;
                float4 s = sk4[gi];
                om4[gi] = make_float4(s.x + ad.x, s.y + ad.y, s.z + ad.z, s.w + ad.w);
            }
            const int tots = 16 * stride * 16;
            for (int id = t; id < tots; id += THR) {
                int child = id >> 4, ch4 = id & 15;
                int ph = child / stride;
                float4 ad = *(const float4*)&ys[ph * YSS + ch4 * 4];
                float4 bb = bs4[ch4];
                size_t gi = (size_t)(cbase + child) * 16 + ch4;
                float4 s = sks4[gi];
                os4[gi] = make_float4(s.x + ad.x + bb.x, s.y + ad.y + bb.y,
                                      s.z + ad.z + bb.z, s.w + ad.w + bb.w);
            }
        }
    }
}

// remainder parents (n_parent % 32): slow scalar path, f32, direct global
__global__ __launch_bounds__(256) void equi_tail(
    const float* __restrict__ x_mv, const float* __restrict__ x_s,
    const float* __restrict__ skip_mv, const float* __restrict__ skip_s,
    const float* __restrict__ w_mv, const float* __restrict__ w_s2mv,
    const float* __restrict__ w_mv2s, const float* __restrict__ w_s2s,
    const float* __restrict__ b_s,
    float* __restrict__ out_mv, float* __restrict__ out_s,
    int pstart, int n_parent, int stride)
{
    int idx = blockIdx.x * blockDim.x + threadIdx.x;
    int o = idx & 31, pr = idx >> 5;
    int p = pstart + pr;
    if (p >= n_parent) return;
    float a[16];
    #pragma unroll
    for (int j = 0; j < 16; ++j) a[j] = 0.f;
    float s0 = 0.f, s1 = 0.f;
    const float4* xg = (const float4*)(x_mv + (size_t)p * 512);
    for (int i = 0; i < 32; ++i) {
        float4 X0 = xg[i * 4 + 0], X1 = xg[i * 4 + 1], X2 = xg[i * 4 + 2], X3 = xg[i * 4 + 3];
        const float* wp = &w_mv[o * 288 + i * 9];
        float w0 = wp[0], w1 = wp[1], w2 = wp[2], w3 = wp[3], w4 = wp[4];
        float w5 = wp[5], w6 = wp[6], w7 = wp[7], w8 = wp[8];
        a[0] += X0.x * w0;  a[1] += X0.y * w1 + X0.x * w5;
        a[2] += X0.z * w1;  a[3] += X0.w * w1;  a[4] += X1.x * w1;
        a[5] += X1.y * w2 + X0.z * w6;  a[6] += X1.z * w2 + X0.w * w6;
        a[7] += X1.w * w2 + X1.x * w6;  a[8] += X2.x * w2;
        a[9] += X2.y * w2;  a[10] += X2.z * w2;
        a[11] += X2.w * w3 + X2.x * w7;  a[12] += X3.x * w3 + X2.y * w7;
        a[13] += X3.y * w3 + X2.z * w7;  a[14] += X3.z * w3;
        a[15] += X3.w * w4 + X3.z * w8;
        s0 += X0.x * w_mv2s[o * 32 + i];
        s1 += X0.x * w_mv2s[(o + 32) * 32 + i];
    }
    for (int sc = 0; sc < 64; ++sc) {
        float xv = x_s[(size_t)p * 64 + sc];
        a[0] += xv * w_s2mv[o * 64 + sc];
        s0 += xv * w_s2s[o * 64 + sc];
        s1 += xv * w_s2s[(o + 32) * 64 + sc];
    }
    s0 += b_s[o]; s1 += b_s[o + 32];
    for (int r = 0; r < stride; ++r) {
        size_t c = (size_t)p * stride + r;
        const float4* sk = (const float4*)(skip_mv + c * 512 + o * 16);
        float4* om = (float4*)(out_mv + c * 512 + o * 16);
        float4 k0 = sk[0], k1 = sk[1], k2 = sk[2], k3 = sk[3];
        om[0] = make_float4(k0.x + a[0],  k0.y + a[1],  k0.z + a[2],  k0.w + a[3]);
        om[1] = make_float4(k1.x + a[4],  k1.y + a[5],  k1.z + a[6],  k1.w + a[7]);
        om[2] = make_float4(k2.x + a[8],  k2.y + a[9],  k2.z + a[10], k2.w + a[11]);
        om[3] = make_float4(k3.x + a[12], k3.y + a[13], k3.z + a[14], k3.w + a[15]);
        out_s[c * 64 + o]      = skip_s[c * 64 + o] + s0;
        out_s[c * 64 + o + 32] = skip_s[c * 64 + o + 32] + s1;
    }
}

extern "C" void kernel_launch(void* const* d_in, const int* in_sizes, int n_in,
                              void* d_out, int out_size, void* d_ws, size_t ws_size,
                              hipStream_t stream) {
    const float* x_mv    = (const float*)d_in[0];
    const float* x_s     = (const float*)d_in[1];
    const float* skip_mv = (const float*)d_in[2];
    const float* skip_s  = (const float*)d_in[3];
    const float* w_mv    = (const float*)d_in[4];
    const float* w_s2mv  = (const float*)d_in[5];
    const float* w_mv2s  = (const float*)d_in[6];
    const float* w_s2s   = (const float*)d_in[7];
    const float* b_s     = (const float*)d_in[8];

    const int n_parent = in_sizes[0] / 512;
    const int n_child  = in_sizes[2] / 512;
    const int stride   = n_child / n_parent;

    float* out_mv = (float*)d_out;
    float* out_s  = out_mv + (size_t)n_child * 512;
    bf16x8* wsf = (bf16x8*)d_ws;   // 13*256*16 = 53248 B

    build_frags<<<1, THR, 0, stream>>>(w_mv, w_s2mv, w_mv2s, w_s2s, wsf);

    const int full = n_parent >> 5;
    const int rem  = n_parent & 31;
    if (full > 0)
        equi_mfma<<<full, THR, 0, stream>>>(
            x_mv, x_s, skip_mv, skip_s, wsf, b_s,
            out_mv, out_s, n_parent, stride);
    if (rem > 0) {
        int thr = rem * 32;
        int blk = (thr + 255) / 256;
        equi_tail<<<blk, 256, 0, stream>>>(
            x_mv, x_s, skip_mv, skip_s, w_mv, w_s2mv, w_mv2s, w_s2s, b_s,
            out_mv, out_s, full * 32, n_parent, stride);
    }
}

// Round 16
// 155.157 us; speedup vs baseline: 1.5818x; 1.0396x over previous
//
#include <hip/hip_runtime.h>

typedef __attribute__((ext_vector_type(8))) short bf16x8;
typedef __attribute__((ext_vector_type(4))) float f32x4;

#define THR 256
#define PBLK 32

__device__ __forceinline__ unsigned int bf_rne(float f) {
    unsigned int u = __float_as_uint(f);
    u += 0x7fffu + ((u >> 16) & 1u);
    return u >> 16;
}

#define MFMA(A, B, C) __builtin_amdgcn_mfma_f32_16x16x32_bf16((A), (B), (C), 0, 0, 0)

// xb u16 index: j-stride 520, slot XOR'd with ig/pl/jq (A-reads/writes ~2-way)
#define XB(ti, j, pl, slot) ((ti) * 8320 + (j) * 520 + (pl) * 32 + (slot) * 8)
#define YPS 520   // y p-stride (f32): 32 o x 16 j + 8 pad
#define YSS 68    // ys p-stride (f32): 64 ch + 4 pad

// ws fragment slots: 0-2 Bg, 3-4 Bw, 5-6 Bm2s, 7-8 Bs2mv, 9-12 Bs2s  -> 13 x 16B x 256 thr
#define NSLOT 13

// ---- one-block init: build per-thread B fragments once, store [slot][tid] ----
__global__ __launch_bounds__(THR) void build_frags(
    const float* __restrict__ w_mv, const float* __restrict__ w_s2mv,
    const float* __restrict__ w_mv2s, const float* __restrict__ w_s2s,
    bf16x8* __restrict__ wsf)
{
    const int t = threadIdx.x;
    const int lane = t & 63;
    const int wid  = t >> 6;
    const int h   = wid & 1;
    const int jh  = wid >> 1;
    const int col = lane & 15;
    const int g4  = lane >> 4;
    const int kb  = g4 * 8;
    const int oo  = h * 16 + col;

    bf16x8 z;
    #pragma unroll
    for (int e = 0; e < 8; ++e) z[e] = 0;

    #pragma unroll
    for (int gg = 0; gg < 3; ++gg) {
        int b = 2 * jh + gg;
        bf16x8 v = z;
        #pragma unroll
        for (int e = 0; e < 8; ++e)
            v[e] = (short)bf_rne(w_mv[oo * 288 + (kb + e) * 9 + b]);
        wsf[gg * THR + t] = v;
    }
    #pragma unroll
    for (int ww = 0; ww < 2; ++ww) {
        int b = 5 + 2 * jh + ww;
        bf16x8 v = z;
        #pragma unroll
        for (int e = 0; e < 8; ++e)
            v[e] = (short)bf_rne(w_mv[oo * 288 + (kb + e) * 9 + b]);
        wsf[(3 + ww) * THR + t] = v;
    }
    if (jh == 0) {
        #pragma unroll
        for (int c = 0; c < 2; ++c) {
            bf16x8 v = z;
            #pragma unroll
            for (int e = 0; e < 8; ++e)
                v[e] = (short)bf_rne(w_mv2s[((2 * h + c) * 16 + col) * 32 + kb + e]);
            wsf[(5 + c) * THR + t] = v;
        }
        #pragma unroll
        for (int kk = 0; kk < 2; ++kk) {
            bf16x8 v = z;
            #pragma unroll
            for (int e = 0; e < 8; ++e)
                v[e] = (short)bf_rne(w_s2mv[oo * 64 + kk * 32 + kb + e]);
            wsf[(7 + kk) * THR + t] = v;
            #pragma unroll
            for (int c = 0; c < 2; ++c) {
                bf16x8 u = z;
                #pragma unroll
                for (int e = 0; e < 8; ++e)
                    u[e] = (short)bf_rne(w_s2s[((2 * h + c) * 16 + col) * 64 + kk * 32 + kb + e]);
                wsf[(9 + kk * 2 + c) * THR + t] = u;
            }
        }
    } else {
        #pragma unroll
        for (int s = 5; s < NSLOT; ++s) wsf[s * THR + t] = z;
    }
}

__global__ __launch_bounds__(THR) void equi_mfma(
    const float* __restrict__ x_mv,    // [Np,32,16]
    const float* __restrict__ x_s,     // [Np,64]
    const float* __restrict__ skip_mv, // [Nc,32,16]
    const float* __restrict__ skip_s,  // [Nc,64]
    const bf16x8* __restrict__ wsf,    // [13][256] precomputed B fragments
    const float* __restrict__ b_s,     // [64]
    float* __restrict__ out_mv,        // [Nc,32,16]
    float* __restrict__ out_s,         // [Nc,64]
    int n_parent, int stride)
{
    // Union LDS. staging view: xb 33280 B + xsb 4096 B = 37376 B.
    // epilogue view: y 16p*520*4 = 33280 B (over xb) + ys 16p*68*4 = 4352 B = 37632 B.
    __shared__ char smem[37632];
    unsigned short* xb  = (unsigned short*)smem;
    unsigned short* xsb = (unsigned short*)(smem + 33280);
    float* y  = (float*)smem;                       // Y(p,o,quad',m) = p*520 + o*16 + quad'*4 + m
    float* ys = (float*)(smem + 33280);             // YS(p,ch) = p*68 + ch

    const int t  = threadIdx.x;
    const int p0 = blockIdx.x * PBLK;

    // ---- stage x_mv -> xb: thread = (p, ig2, jq); 16 f4 loads -> 8 ds_write_b128 ----
    {
        const int p   = t >> 3;
        const int ig2 = (t >> 2) & 1;
        const int jq  = t & 3;
        const int ti  = p >> 4, pl = p & 15;
        const float4* xg = (const float4*)(x_mv + (size_t)p0 * 512);
        const int base = p * 128 + ig2 * 64 + jq;
        bf16x8 acc[4][2];     // [jo][igl]
        #pragma unroll
        for (int s = 0; s < 16; ++s) {
            float4 v = xg[base + s * 4];
            int igl = s >> 3, e = s & 7;
            acc[0][igl][e] = (short)bf_rne(v.x);
            acc[1][igl][e] = (short)bf_rne(v.y);
            acc[2][igl][e] = (short)bf_rne(v.z);
            acc[3][igl][e] = (short)bf_rne(v.w);
        }
        #pragma unroll
        for (int jo = 0; jo < 4; ++jo)
            #pragma unroll
            for (int igl = 0; igl < 2; ++igl) {
                int ig = ig2 * 2 + igl;
                int slot = ig ^ (pl & 3) ^ jq;
                *(bf16x8*)&xb[XB(ti, jq * 4 + jo, pl, slot)] = acc[jo][igl];
            }
        // x_s -> xsb: thread = (p, q); 2 f4 loads -> 1 ds_write_b128
        const int q = t & 7;
        const int ps = t >> 3;
        const int tis = ps >> 4, pls = ps & 15;
        const float4* xsg = (const float4*)(x_s + (size_t)p0 * 64);
        float4 v0 = xsg[ps * 16 + q * 2 + 0];
        float4 v1 = xsg[ps * 16 + q * 2 + 1];
        bf16x8 sv;
        sv[0] = (short)bf_rne(v0.x); sv[1] = (short)bf_rne(v0.y);
        sv[2] = (short)bf_rne(v0.z); sv[3] = (short)bf_rne(v0.w);
        sv[4] = (short)bf_rne(v1.x); sv[5] = (short)bf_rne(v1.y);
        sv[6] = (short)bf_rne(v1.z); sv[7] = (short)bf_rne(v1.w);
        *(bf16x8*)&xsb[((tis * 16 + pls) * 8 + (q ^ (pls & 7))) * 8] = sv;
    }

    // ---- load precomputed B fragments: 13 coalesced dwordx4 (L2-hot) ----
    const int lane = t & 63;
    const int wid  = t >> 6;
    const int h   = wid & 1;
    const int jh  = wid >> 1;
    const int col = lane & 15;
    const int g4  = lane >> 4;
    const int oo  = h * 16 + col;

    bf16x8 Bg[3], Bw[2], Bm2s[2], Bs2mv[2], Bs2s[2][2];
    Bg[0]      = wsf[0 * THR + t];
    Bg[1]      = wsf[1 * THR + t];
    Bg[2]      = wsf[2 * THR + t];
    Bw[0]      = wsf[3 * THR + t];
    Bw[1]      = wsf[4 * THR + t];
    Bm2s[0]    = wsf[5 * THR + t];
    Bm2s[1]    = wsf[6 * THR + t];
    Bs2mv[0]   = wsf[7 * THR + t];
    Bs2mv[1]   = wsf[8 * THR + t];
    Bs2s[0][0] = wsf[9 * THR + t];
    Bs2s[0][1] = wsf[10 * THR + t];
    Bs2s[1][0] = wsf[11 * THR + t];
    Bs2s[1][1] = wsf[12 * THR + t];

    __syncthreads();   // barrier #1: xb/xsb ready

    // ---- MFMA phase ----
    f32x4 cj[2][8];
    f32x4 cs[2][2];
    #pragma unroll
    for (int ti = 0; ti < 2; ++ti) {
        #pragma unroll
        for (int jj = 0; jj < 8; ++jj) cj[ti][jj] = (f32x4){0.f, 0.f, 0.f, 0.f};
        cs[ti][0] = (f32x4){0.f, 0.f, 0.f, 0.f};
        cs[ti][1] = (f32x4){0.f, 0.f, 0.f, 0.f};
    }
    const int prow = col;

    if (jh == 0) {
        #pragma unroll
        for (int ti = 0; ti < 2; ++ti) {
            bf16x8 A0;
            #pragma unroll
            for (int jj = 0; jj < 8; ++jj) {
                int slot = g4 ^ (prow & 3) ^ (jj >> 2);
                bf16x8 A = *(const bf16x8*)&xb[XB(ti, jj, prow, slot)];
                if (jj == 0)      cj[ti][0] = MFMA(A, Bg[0], cj[ti][0]);
                else if (jj < 5)  cj[ti][jj] = MFMA(A, Bg[1], cj[ti][jj]);
                else              cj[ti][jj] = MFMA(A, Bg[2], cj[ti][jj]);
                if (jj == 0) { cj[ti][1] = MFMA(A, Bw[0], cj[ti][1]); A0 = A; }
                else if (jj == 2) cj[ti][5] = MFMA(A, Bw[1], cj[ti][5]);
                else if (jj == 3) cj[ti][6] = MFMA(A, Bw[1], cj[ti][6]);
                else if (jj == 4) cj[ti][7] = MFMA(A, Bw[1], cj[ti][7]);
            }
            cs[ti][0] = MFMA(A0, Bm2s[0], cs[ti][0]);
            cs[ti][1] = MFMA(A0, Bm2s[1], cs[ti][1]);
            #pragma unroll
            for (int kk = 0; kk < 2; ++kk) {
                const unsigned short* sp = &xsb[((ti * 16 + prow) * 8 + ((kk * 4 + g4) ^ (prow & 7))) * 8];
                bf16x8 Axs = *(const bf16x8*)sp;
                cj[ti][0] = MFMA(Axs, Bs2mv[kk], cj[ti][0]);
                cs[ti][0] = MFMA(Axs, Bs2s[kk][0], cs[ti][0]);
                cs[ti][1] = MFMA(Axs, Bs2s[kk][1], cs[ti][1]);
            }
        }
    } else {
        #pragma unroll
        for (int ti = 0; ti < 2; ++ti) {
            #pragma unroll
            for (int jj = 0; jj < 8; ++jj) {
                int j = 8 + jj;
                int slot = g4 ^ (prow & 3) ^ (j >> 2);
                bf16x8 A = *(const bf16x8*)&xb[XB(ti, j, prow, slot)];
                if (jj < 3)       cj[ti][jj] = MFMA(A, Bg[0], cj[ti][jj]);
                else if (jj < 7)  cj[ti][jj] = MFMA(A, Bg[1], cj[ti][jj]);
                else              cj[ti][jj] = MFMA(A, Bg[2], cj[ti][jj]);
                if (jj == 0)      cj[ti][3] = MFMA(A, Bw[0], cj[ti][3]);
                else if (jj == 1) cj[ti][4] = MFMA(A, Bw[0], cj[ti][4]);
                else if (jj == 2) cj[ti][5] = MFMA(A, Bw[0], cj[ti][5]);
                else if (jj == 6) cj[ti][7] = MFMA(A, Bw[1], cj[ti][7]);
            }
        }
    }

    // ---- epilogue: 2 half-tiles of 16 parents; vectorized C->y then batched stream ----
    #pragma unroll
    for (int hf = 0; hf < 2; ++hf) {
        __syncthreads();   // xb/xsb dead (hf=0) / prev y-reads done (hf=1)
        #pragma unroll
        for (int r = 0; r < 4; ++r) {
            int p = g4 * 4 + r;
            #pragma unroll
            for (int q4 = 0; q4 < 2; ++q4) {
                int jqg  = jh * 2 + q4;                 // global j-quad
                int quad = jqg ^ (oo & 3) ^ g4;         // g4 == p>>2
                float4 w;
                w.x = cj[hf][q4 * 4 + 0][r];
                w.y = cj[hf][q4 * 4 + 1][r];
                w.z = cj[hf][q4 * 4 + 2][r];
                w.w = cj[hf][q4 * 4 + 3][r];
                *(float4*)&y[p * YPS + oo * 16 + quad * 4] = w;
            }
        }
        if (jh == 0) {
            #pragma unroll
            for (int c = 0; c < 2; ++c)
                #pragma unroll
                for (int r = 0; r < 4; ++r)
                    ys[(g4 * 4 + r) * YSS + (2 * h + c) * 16 + col] = cs[hf][c][r];
        }
        __syncthreads();   // y ready

        const int cbase = (p0 + hf * 16) * stride;
        const float4* sk4 = (const float4*)skip_mv;
        float4* om4 = (float4*)out_mv;
        const float4* sks4 = (const float4*)skip_s;
        float4* os4 = (float4*)out_s;
        const float4* bs4 = (const float4*)b_s;

        if (stride == 2) {
            // 4096 f4 / 256 thr = 16 iters -> 4 batches of 4 (>=4 loads in flight)
            #pragma unroll
            for (int bt = 0; bt < 4; ++bt) {
                size_t gidx[4];
                float4 sv[4], yv[4];
                #pragma unroll
                for (int u = 0; u < 4; ++u) {
                    int id = t + (bt * 4 + u) * THR;
                    int child = id >> 7, rem = id & 127;
                    int o = rem >> 2, q = rem & 3;
                    int ph = child >> 1;
                    int quad = q ^ (o & 3) ^ (ph >> 2);
                    gidx[u] = (size_t)(cbase + child) * 128 + rem;
                    sv[u] = sk4[gidx[u]];
                    yv[u] = *(const float4*)&y[ph * YPS + o * 16 + quad * 4];
                }
                #pragma unroll
                for (int u = 0; u < 4; ++u)
                    om4[gidx[u]] = make_float4(sv[u].x + yv[u].x, sv[u].y + yv[u].y,
                                               sv[u].z + yv[u].z, sv[u].w + yv[u].w);
            }
            // 512 f4 / 256 thr = 2 iters -> 1 batch of 2
            {
                size_t gidx[2];
                float4 sv[2], av[2];
                #pragma unroll
                for (int u = 0; u < 2; ++u) {
                    int id = t + u * THR;
                    int child = id >> 4, ch4 = id & 15;
                    int ph = child >> 1;
                    float4 ad = *(const float4*)&ys[ph * YSS + ch4 * 4];
                    float4 bb = bs4[ch4];
                    gidx[u] = (size_t)(cbase + child) * 16 + ch4;
                    sv[u] = sks4[gidx[u]];
                    av[u] = make_float4(ad.x + bb.x, ad.y + bb.y, ad.z + bb.z, ad.w + bb.w);
                }
                #pragma unroll
                for (int u = 0; u < 2; ++u)
                    os4[gidx[u]] = make_float4(sv[u].x + av[u].x, sv[u].y + av[u].y,
                                               sv[u].z + av[u].z, sv[u].w + av[u].w);
            }
        } else {
            const int totmv = 16 * stride * 128;
            for (int id = t; id < totmv; id += THR) {
                int child = id >> 7, rem = id & 127;
                int o = rem >> 2, q = rem & 3;
                int ph = child / stride;
                int quad = q ^ (o & 3) ^ (ph >> 2);
                float4 ad = *(const float4*)&y[ph * YPS + o * 16 + quad * 4];
                size_t gi = (size_t)(cbase + child) * 128 + rem;
                float4 s = sk4[gi];
                om4[gi] = make_float4(s.x + ad.x, s.y + ad.y, s.z + ad.z, s.w + ad.w);
            }
            const int tots = 16 * stride * 16;
            for (int id = t; id < tots; id += THR) {
                int child = id >> 4, ch4 = id & 15;
                int ph = child / stride;
                float4 ad = *(const float4*)&ys[ph * YSS + ch4 * 4];
                float4 bb = bs4[ch4];
                size_t gi = (size_t)(cbase + child) * 16 + ch4;
                float4 s = sks4[gi];
                os4[gi] = make_float4(s.x + ad.x + bb.x, s.y + ad.y + bb.y,
                                      s.z + ad.z + bb.z, s.w + ad.w + bb.w);
            }
        }
    }
}

// remainder parents (n_parent % 32): slow scalar path, f32, direct global
__global__ __launch_bounds__(256) void equi_tail(
    const float* __restrict__ x_mv, const float* __restrict__ x_s,
    const float* __restrict__ skip_mv, const float* __restrict__ skip_s,
    const float* __restrict__ w_mv, const float* __restrict__ w_s2mv,
    const float* __restrict__ w_mv2s, const float* __restrict__ w_s2s,
    const float* __restrict__ b_s,
    float* __restrict__ out_mv, float* __restrict__ out_s,
    int pstart, int n_parent, int stride)
{
    int idx = blockIdx.x * blockDim.x + threadIdx.x;
    int o = idx & 31, pr = idx >> 5;
    int p = pstart + pr;
    if (p >= n_parent) return;
    float a[16];
    #pragma unroll
    for (int j = 0; j < 16; ++j) a[j] = 0.f;
    float s0 = 0.f, s1 = 0.f;
    const float4* xg = (const float4*)(x_mv + (size_t)p * 512);
    for (int i = 0; i < 32; ++i) {
        float4 X0 = xg[i * 4 + 0], X1 = xg[i * 4 + 1], X2 = xg[i * 4 + 2], X3 = xg[i * 4 + 3];
        const float* wp = &w_mv[o * 288 + i * 9];
        float w0 = wp[0], w1 = wp[1], w2 = wp[2], w3 = wp[3], w4 = wp[4];
        float w5 = wp[5], w6 = wp[6], w7 = wp[7], w8 = wp[8];
        a[0] += X0.x * w0;  a[1] += X0.y * w1 + X0.x * w5;
        a[2] += X0.z * w1;  a[3] += X0.w * w1;  a[4] += X1.x * w1;
        a[5] += X1.y * w2 + X0.z * w6;  a[6] += X1.z * w2 + X0.w * w6;
        a[7] += X1.w * w2 + X1.x * w6;  a[8] += X2.x * w2;
        a[9] += X2.y * w2;  a[10] += X2.z * w2;
        a[11] += X2.w * w3 + X2.x * w7;  a[12] += X3.x * w3 + X2.y * w7;
        a[13] += X3.y * w3 + X2.z * w7;  a[14] += X3.z * w3;
        a[15] += X3.w * w4 + X3.z * w8;
        s0 += X0.x * w_mv2s[o * 32 + i];
        s1 += X0.x * w_mv2s[(o + 32) * 32 + i];
    }
    for (int sc = 0; sc < 64; ++sc) {
        float xv = x_s[(size_t)p * 64 + sc];
        a[0] += xv * w_s2mv[o * 64 + sc];
        s0 += xv * w_s2s[o * 64 + sc];
        s1 += xv * w_s2s[(o + 32) * 64 + sc];
    }
    s0 += b_s[o]; s1 += b_s[o + 32];
    for (int r = 0; r < stride; ++r) {
        size_t c = (size_t)p * stride + r;
        const float4* sk = (const float4*)(skip_mv + c * 512 + o * 16);
        float4* om = (float4*)(out_mv + c * 512 + o * 16);
        float4 k0 = sk[0], k1 = sk[1], k2 = sk[2], k3 = sk[3];
        om[0] = make_float4(k0.x + a[0],  k0.y + a[1],  k0.z + a[2],  k0.w + a[3]);
        om[1] = make_float4(k1.x + a[4],  k1.y + a[5],  k1.z + a[6],  k1.w + a[7]);
        om[2] = make_float4(k2.x + a[8],  k2.y + a[9],  k2.z + a[10], k2.w + a[11]);
        om[3] = make_float4(k3.x + a[12], k3.y + a[13], k3.z + a[14], k3.w + a[15]);
        out_s[c * 64 + o]      = skip_s[c * 64 + o] + s0;
        out_s[c * 64 + o + 32] = skip_s[c * 64 + o + 32] + s1;
    }
}

extern "C" void kernel_launch(void* const* d_in, const int* in_sizes, int n_in,
                              void* d_out, int out_size, void* d_ws, size_t ws_size,
                              hipStream_t stream) {
    const float* x_mv    = (const float*)d_in[0];
    const float* x_s     = (const float*)d_in[1];
    const float* skip_mv = (const float*)d_in[2];
    const float* skip_s  = (const float*)d_in[3];
    const float* w_mv    = (const float*)d_in[4];
    const float* w_s2mv  = (const float*)d_in[5];
    const float* w_mv2s  = (const float*)d_in[6];
    const float* w_s2s   = (const float*)d_in[7];
    const float* b_s     = (const float*)d_in[8];

    const int n_parent = in_sizes[0] / 512;
    const int n_child  = in_sizes[2] / 512;
    const int stride   = n_child / n_parent;

    float* out_mv = (float*)d_out;
    float* out_s  = out_mv + (size_t)n_child * 512;
    bf16x8* wsf = (bf16x8*)d_ws;   // 13*256*16 = 53248 B

    build_frags<<<1, THR, 0, stream>>>(w_mv, w_s2mv, w_mv2s, w_s2s, wsf);

    const int full = n_parent >> 5;
    const int rem  = n_parent & 31;
    if (full > 0)
        equi_mfma<<<full, THR, 0, stream>>>(
            x_mv, x_s, skip_mv, skip_s, wsf, b_s,
            out_mv, out_s, n_parent, stride);
    if (rem > 0) {
        int thr = rem * 32;
        int blk = (thr + 255) / 256;
        equi_tail<<<blk, 256, 0, stream>>>(
            x_mv, x_s, skip_mv, skip_s, w_mv, w_s2mv, w_mv2s, w_s2s, b_s,
            out_mv, out_s, full * 32, n_parent, stride);
    }
}

// Round 17
// 153.763 us; speedup vs baseline: 1.5962x; 1.0091x over previous
//
#include <hip/hip_runtime.h>

typedef __attribute__((ext_vector_type(8))) short bf16x8;
typedef __attribute__((ext_vector_type(4))) float f32x4;

#define THR 256
#define PBLK 32

__device__ __forceinline__ unsigned int bf_rne(float f) {
    unsigned int u = __float_as_uint(f);
    u += 0x7fffu + ((u >> 16) & 1u);
    return u >> 16;
}
__device__ __forceinline__ unsigned int pack2(float a, float b) {
    return bf_rne(a) | (bf_rne(b) << 16);
}
__device__ __forceinline__ float bf_lo(unsigned int u) { return __uint_as_float(u << 16); }
__device__ __forceinline__ float bf_hi(unsigned int u) { return __uint_as_float(u & 0xffff0000u); }

#define MFMA(A, B, C) __builtin_amdgcn_mfma_f32_16x16x32_bf16((A), (B), (C), 0, 0, 0)

// xb u16 index: j-stride 520, slot XOR'd with ig/pl/jq (A-reads/writes ~2-way)
#define XB(ti, j, pl, slot) ((ti) * 8320 + (j) * 520 + (pl) * 32 + (slot) * 8)
#define YPS 520   // y p-stride in u16 (bf16 delta): 32 o x 16 j + 8 pad
#define YSS 68    // ys p-stride in u16

#define NSLOT 13

// ---- one-block init: build per-thread B fragments once, store [slot][tid] ----
__global__ __launch_bounds__(THR) void build_frags(
    const float* __restrict__ w_mv, const float* __restrict__ w_s2mv,
    const float* __restrict__ w_mv2s, const float* __restrict__ w_s2s,
    bf16x8* __restrict__ wsf)
{
    const int t = threadIdx.x;
    const int lane = t & 63;
    const int wid  = t >> 6;
    const int h   = wid & 1;
    const int jh  = wid >> 1;
    const int col = lane & 15;
    const int g4  = lane >> 4;
    const int kb  = g4 * 8;
    const int oo  = h * 16 + col;

    bf16x8 z;
    #pragma unroll
    for (int e = 0; e < 8; ++e) z[e] = 0;

    #pragma unroll
    for (int gg = 0; gg < 3; ++gg) {
        int b = 2 * jh + gg;
        bf16x8 v = z;
        #pragma unroll
        for (int e = 0; e < 8; ++e)
            v[e] = (short)bf_rne(w_mv[oo * 288 + (kb + e) * 9 + b]);
        wsf[gg * THR + t] = v;
    }
    #pragma unroll
    for (int ww = 0; ww < 2; ++ww) {
        int b = 5 + 2 * jh + ww;
        bf16x8 v = z;
        #pragma unroll
        for (int e = 0; e < 8; ++e)
            v[e] = (short)bf_rne(w_mv[oo * 288 + (kb + e) * 9 + b]);
        wsf[(3 + ww) * THR + t] = v;
    }
    if (jh == 0) {
        #pragma unroll
        for (int c = 0; c < 2; ++c) {
            bf16x8 v = z;
            #pragma unroll
            for (int e = 0; e < 8; ++e)
                v[e] = (short)bf_rne(w_mv2s[((2 * h + c) * 16 + col) * 32 + kb + e]);
            wsf[(5 + c) * THR + t] = v;
        }
        #pragma unroll
        for (int kk = 0; kk < 2; ++kk) {
            bf16x8 v = z;
            #pragma unroll
            for (int e = 0; e < 8; ++e)
                v[e] = (short)bf_rne(w_s2mv[oo * 64 + kk * 32 + kb + e]);
            wsf[(7 + kk) * THR + t] = v;
            #pragma unroll
            for (int c = 0; c < 2; ++c) {
                bf16x8 u = z;
                #pragma unroll
                for (int e = 0; e < 8; ++e)
                    u[e] = (short)bf_rne(w_s2s[((2 * h + c) * 16 + col) * 64 + kk * 32 + kb + e]);
                wsf[(9 + kk * 2 + c) * THR + t] = u;
            }
        }
    } else {
        #pragma unroll
        for (int s = 5; s < NSLOT; ++s) wsf[s * THR + t] = z;
    }
}

__global__ __launch_bounds__(THR) void equi_mfma(
    const float* __restrict__ x_mv,    // [Np,32,16]
    const float* __restrict__ x_s,     // [Np,64]
    const float* __restrict__ skip_mv, // [Nc,32,16]
    const float* __restrict__ skip_s,  // [Nc,64]
    const bf16x8* __restrict__ wsf,    // [13][256] precomputed B fragments
    const float* __restrict__ b_s,     // [64]
    float* __restrict__ out_mv,        // [Nc,32,16]
    float* __restrict__ out_s,         // [Nc,64]
    int n_parent, int stride)
{
    // Union LDS. staging view: xb 33280 B + xsb 4096 B.
    // epilogue view (bf16 delta): yb 32p*520*2 = 33280 B + ysb 32p*68*2 = 4352 B = 37632 B.
    __shared__ char smem[37632];
    unsigned short* xb  = (unsigned short*)smem;
    unsigned short* xsb = (unsigned short*)(smem + 33280);
    unsigned short* yb  = (unsigned short*)smem;            // Y(p,o,quad,m) bf16
    unsigned short* ysb = (unsigned short*)(smem + 33280);  // YS(p,ch) bf16

    const int t  = threadIdx.x;
    const int p0 = blockIdx.x * PBLK;

    // ---- stage x_mv -> xb: thread = (p, ig2, jq); 16 f4 loads -> 8 ds_write_b128 ----
    {
        const int p   = t >> 3;
        const int ig2 = (t >> 2) & 1;
        const int jq  = t & 3;
        const int ti  = p >> 4, pl = p & 15;
        const float4* xg = (const float4*)(x_mv + (size_t)p0 * 512);
        const int base = p * 128 + ig2 * 64 + jq;
        bf16x8 acc[4][2];     // [jo][igl]
        #pragma unroll
        for (int s = 0; s < 16; ++s) {
            float4 v = xg[base + s * 4];
            int igl = s >> 3, e = s & 7;
            acc[0][igl][e] = (short)bf_rne(v.x);
            acc[1][igl][e] = (short)bf_rne(v.y);
            acc[2][igl][e] = (short)bf_rne(v.z);
            acc[3][igl][e] = (short)bf_rne(v.w);
        }
        #pragma unroll
        for (int jo = 0; jo < 4; ++jo)
            #pragma unroll
            for (int igl = 0; igl < 2; ++igl) {
                int ig = ig2 * 2 + igl;
                int slot = ig ^ (pl & 3) ^ jq;
                *(bf16x8*)&xb[XB(ti, jq * 4 + jo, pl, slot)] = acc[jo][igl];
            }
        // x_s -> xsb: thread = (p, q); 2 f4 loads -> 1 ds_write_b128
        const int q = t & 7;
        const int ps = t >> 3;
        const int tis = ps >> 4, pls = ps & 15;
        const float4* xsg = (const float4*)(x_s + (size_t)p0 * 64);
        float4 v0 = xsg[ps * 16 + q * 2 + 0];
        float4 v1 = xsg[ps * 16 + q * 2 + 1];
        bf16x8 sv;
        sv[0] = (short)bf_rne(v0.x); sv[1] = (short)bf_rne(v0.y);
        sv[2] = (short)bf_rne(v0.z); sv[3] = (short)bf_rne(v0.w);
        sv[4] = (short)bf_rne(v1.x); sv[5] = (short)bf_rne(v1.y);
        sv[6] = (short)bf_rne(v1.z); sv[7] = (short)bf_rne(v1.w);
        *(bf16x8*)&xsb[((tis * 16 + pls) * 8 + (q ^ (pls & 7))) * 8] = sv;
    }

    // ---- load precomputed B fragments: 13 coalesced dwordx4 (L2-hot) ----
    const int lane = t & 63;
    const int wid  = t >> 6;
    const int h   = wid & 1;
    const int jh  = wid >> 1;
    const int col = lane & 15;
    const int g4  = lane >> 4;
    const int oo  = h * 16 + col;

    bf16x8 Bg[3], Bw[2], Bm2s[2], Bs2mv[2], Bs2s[2][2];
    Bg[0]      = wsf[0 * THR + t];
    Bg[1]      = wsf[1 * THR + t];
    Bg[2]      = wsf[2 * THR + t];
    Bw[0]      = wsf[3 * THR + t];
    Bw[1]      = wsf[4 * THR + t];
    Bm2s[0]    = wsf[5 * THR + t];
    Bm2s[1]    = wsf[6 * THR + t];
    Bs2mv[0]   = wsf[7 * THR + t];
    Bs2mv[1]   = wsf[8 * THR + t];
    Bs2s[0][0] = wsf[9 * THR + t];
    Bs2s[0][1] = wsf[10 * THR + t];
    Bs2s[1][0] = wsf[11 * THR + t];
    Bs2s[1][1] = wsf[12 * THR + t];

    __syncthreads();   // barrier #1: xb/xsb ready

    // ---- MFMA phase ----
    f32x4 cj[2][8];
    f32x4 cs[2][2];
    #pragma unroll
    for (int ti = 0; ti < 2; ++ti) {
        #pragma unroll
        for (int jj = 0; jj < 8; ++jj) cj[ti][jj] = (f32x4){0.f, 0.f, 0.f, 0.f};
        cs[ti][0] = (f32x4){0.f, 0.f, 0.f, 0.f};
        cs[ti][1] = (f32x4){0.f, 0.f, 0.f, 0.f};
    }
    const int prow = col;

    if (jh == 0) {
        #pragma unroll
        for (int ti = 0; ti < 2; ++ti) {
            bf16x8 A0;
            #pragma unroll
            for (int jj = 0; jj < 8; ++jj) {
                int slot = g4 ^ (prow & 3) ^ (jj >> 2);
                bf16x8 A = *(const bf16x8*)&xb[XB(ti, jj, prow, slot)];
                if (jj == 0)      cj[ti][0] = MFMA(A, Bg[0], cj[ti][0]);
                else if (jj < 5)  cj[ti][jj] = MFMA(A, Bg[1], cj[ti][jj]);
                else              cj[ti][jj] = MFMA(A, Bg[2], cj[ti][jj]);
                if (jj == 0) { cj[ti][1] = MFMA(A, Bw[0], cj[ti][1]); A0 = A; }
                else if (jj == 2) cj[ti][5] = MFMA(A, Bw[1], cj[ti][5]);
                else if (jj == 3) cj[ti][6] = MFMA(A, Bw[1], cj[ti][6]);
                else if (jj == 4) cj[ti][7] = MFMA(A, Bw[1], cj[ti][7]);
            }
            cs[ti][0] = MFMA(A0, Bm2s[0], cs[ti][0]);
            cs[ti][1] = MFMA(A0, Bm2s[1], cs[ti][1]);
            #pragma unroll
            for (int kk = 0; kk < 2; ++kk) {
                const unsigned short* sp = &xsb[((ti * 16 + prow) * 8 + ((kk * 4 + g4) ^ (prow & 7))) * 8];
                bf16x8 Axs = *(const bf16x8*)sp;
                cj[ti][0] = MFMA(Axs, Bs2mv[kk], cj[ti][0]);
                cs[ti][0] = MFMA(Axs, Bs2s[kk][0], cs[ti][0]);
                cs[ti][1] = MFMA(Axs, Bs2s[kk][1], cs[ti][1]);
            }
        }
    } else {
        #pragma unroll
        for (int ti = 0; ti < 2; ++ti) {
            #pragma unroll
            for (int jj = 0; jj < 8; ++jj) {
                int j = 8 + jj;
                int slot = g4 ^ (prow & 3) ^ (j >> 2);
                bf16x8 A = *(const bf16x8*)&xb[XB(ti, j, prow, slot)];
                if (jj < 3)       cj[ti][jj] = MFMA(A, Bg[0], cj[ti][jj]);
                else if (jj < 7)  cj[ti][jj] = MFMA(A, Bg[1], cj[ti][jj]);
                else              cj[ti][jj] = MFMA(A, Bg[2], cj[ti][jj]);
                if (jj == 0)      cj[ti][3] = MFMA(A, Bw[0], cj[ti][3]);
                else if (jj == 1) cj[ti][4] = MFMA(A, Bw[0], cj[ti][4]);
                else if (jj == 2) cj[ti][5] = MFMA(A, Bw[0], cj[ti][5]);
                else if (jj == 6) cj[ti][7] = MFMA(A, Bw[1], cj[ti][7]);
            }
        }
    }

    // ---- single transpose: ALL C -> yb/ysb (bf16); accs die here ----
    __syncthreads();   // barrier #2: all xb/xsb reads complete (yb overlays xb)
    #pragma unroll
    for (int ti = 0; ti < 2; ++ti)
        #pragma unroll
        for (int r = 0; r < 4; ++r) {
            int p = ti * 16 + g4 * 4 + r;
            #pragma unroll
            for (int q4 = 0; q4 < 2; ++q4) {
                int jqg  = jh * 2 + q4;
                int quad = jqg ^ (oo & 3) ^ (col >> 2) ^ g4;   // (oo>>2)&3 == col>>2
                uint2 w;
                w.x = pack2(cj[ti][q4 * 4 + 0][r], cj[ti][q4 * 4 + 1][r]);
                w.y = pack2(cj[ti][q4 * 4 + 2][r], cj[ti][q4 * 4 + 3][r]);
                *(uint2*)&yb[p * YPS + oo * 16 + quad * 4] = w;
            }
        }
    if (jh == 0) {
        #pragma unroll
        for (int ti = 0; ti < 2; ++ti)
            #pragma unroll
            for (int c = 0; c < 2; ++c)
                #pragma unroll
                for (int r = 0; r < 4; ++r)
                    ysb[(ti * 16 + g4 * 4 + r) * YSS + (2 * h + c) * 16 + col] =
                        (unsigned short)bf_rne(cs[ti][c][r]);
    }
    __syncthreads();   // barrier #3: y ready

    // ---- streaming epilogue: one contiguous batch-8 pipelined stream ----
    const int cbase = p0 * stride;
    const float4* sk4 = (const float4*)skip_mv;
    float4* om4 = (float4*)out_mv;
    const float4* sks4 = (const float4*)skip_s;
    float4* os4 = (float4*)out_s;
    const float4* bs4 = (const float4*)b_s;

    if (stride == 2) {
        // mv: 32p*2c*128 f4 = 8192 / 256 thr = 32 iters -> 4 batches of 8
        #pragma unroll
        for (int bt = 0; bt < 4; ++bt) {
            size_t gidx[8];
            float4 sv[8];
            uint2  yv[8];
            #pragma unroll
            for (int u = 0; u < 8; ++u) {
                int id = t + (bt * 8 + u) * THR;
                int child = id >> 7, rem = id & 127;
                int o = rem >> 2, q = rem & 3;
                int ph = child >> 1;
                int quad = q ^ (o & 3) ^ ((o >> 2) & 3) ^ ((ph >> 2) & 3);
                gidx[u] = (size_t)(cbase + child) * 128 + rem;
                sv[u] = sk4[gidx[u]];
                yv[u] = *(const uint2*)&yb[ph * YPS + o * 16 + quad * 4];
            }
            #pragma unroll
            for (int u = 0; u < 8; ++u)
                om4[gidx[u]] = make_float4(sv[u].x + bf_lo(yv[u].x), sv[u].y + bf_hi(yv[u].x),
                                           sv[u].z + bf_lo(yv[u].y), sv[u].w + bf_hi(yv[u].y));
        }
        // s: 64c*16 f4 = 1024 / 256 = 4 iters -> 1 batch of 4
        {
            size_t gidx[4];
            float4 sv[4], av[4];
            #pragma unroll
            for (int u = 0; u < 4; ++u) {
                int id = t + u * THR;
                int child = id >> 4, ch4 = id & 15;
                int ph = child >> 1;
                uint2 yv = *(const uint2*)&ysb[ph * YSS + ch4 * 4];
                float4 bb = bs4[ch4];
                av[u] = make_float4(bf_lo(yv.x) + bb.x, bf_hi(yv.x) + bb.y,
                                    bf_lo(yv.y) + bb.z, bf_hi(yv.y) + bb.w);
                gidx[u] = (size_t)(cbase + child) * 16 + ch4;
                sv[u] = sks4[gidx[u]];
            }
            #pragma unroll
            for (int u = 0; u < 4; ++u)
                os4[gidx[u]] = make_float4(sv[u].x + av[u].x, sv[u].y + av[u].y,
                                           sv[u].z + av[u].z, sv[u].w + av[u].w);
        }
    } else {
        const int totmv = PBLK * stride * 128;
        for (int id = t; id < totmv; id += THR) {
            int child = id >> 7, rem = id & 127;
            int o = rem >> 2, q = rem & 3;
            int ph = child / stride;
            int quad = q ^ (o & 3) ^ ((o >> 2) & 3) ^ ((ph >> 2) & 3);
            uint2 yv = *(const uint2*)&yb[ph * YPS + o * 16 + quad * 4];
            size_t gi = (size_t)(cbase + child) * 128 + rem;
            float4 s = sk4[gi];
            om4[gi] = make_float4(s.x + bf_lo(yv.x), s.y + bf_hi(yv.x),
                                  s.z + bf_lo(yv.y), s.w + bf_hi(yv.y));
        }
        const int tots = PBLK * stride * 16;
        for (int id = t; id < tots; id += THR) {
            int child = id >> 4, ch4 = id & 15;
            int ph = child / stride;
            uint2 yv = *(const uint2*)&ysb[ph * YSS + ch4 * 4];
            float4 bb = bs4[ch4];
            size_t gi = (size_t)(cbase + child) * 16 + ch4;
            float4 s = sks4[gi];
            os4[gi] = make_float4(s.x + bf_lo(yv.x) + bb.x, s.y + bf_hi(yv.x) + bb.y,
                                  s.z + bf_lo(yv.y) + bb.z, s.w + bf_hi(yv.y) + bb.w);
        }
    }
}

// remainder parents (n_parent % 32): slow scalar path, f32, direct global
__global__ __launch_bounds__(256) void equi_tail(
    const float* __restrict__ x_mv, const float* __restrict__ x_s,
    const float* __restrict__ skip_mv, const float* __restrict__ skip_s,
    const float* __restrict__ w_mv, const float* __restrict__ w_s2mv,
    const float* __restrict__ w_mv2s, const float* __restrict__ w_s2s,
    const float* __restrict__ b_s,
    float* __restrict__ out_mv, float* __restrict__ out_s,
    int pstart, int n_parent, int stride)
{
    int idx = blockIdx.x * blockDim.x + threadIdx.x;
    int o = idx & 31, pr = idx >> 5;
    int p = pstart + pr;
    if (p >= n_parent) return;
    float a[16];
    #pragma unroll
    for (int j = 0; j < 16; ++j) a[j] = 0.f;
    float s0 = 0.f, s1 = 0.f;
    const float4* xg = (const float4*)(x_mv + (size_t)p * 512);
    for (int i = 0; i < 32; ++i) {
        float4 X0 = xg[i * 4 + 0], X1 = xg[i * 4 + 1], X2 = xg[i * 4 + 2], X3 = xg[i * 4 + 3];
        const float* wp = &w_mv[o * 288 + i * 9];
        float w0 = wp[0], w1 = wp[1], w2 = wp[2], w3 = wp[3], w4 = wp[4];
        float w5 = wp[5], w6 = wp[6], w7 = wp[7], w8 = wp[8];
        a[0] += X0.x * w0;  a[1] += X0.y * w1 + X0.x * w5;
        a[2] += X0.z * w1;  a[3] += X0.w * w1;  a[4] += X1.x * w1;
        a[5] += X1.y * w2 + X0.z * w6;  a[6] += X1.z * w2 + X0.w * w6;
        a[7] += X1.w * w2 + X1.x * w6;  a[8] += X2.x * w2;
        a[9] += X2.y * w2;  a[10] += X2.z * w2;
        a[11] += X2.w * w3 + X2.x * w7;  a[12] += X3.x * w3 + X2.y * w7;
        a[13] += X3.y * w3 + X2.z * w7;  a[14] += X3.z * w3;
        a[15] += X3.w * w4 + X3.z * w8;
        s0 += X0.x * w_mv2s[o * 32 + i];
        s1 += X0.x * w_mv2s[(o + 32) * 32 + i];
    }
    for (int sc = 0; sc < 64; ++sc) {
        float xv = x_s[(size_t)p * 64 + sc];
        a[0] += xv * w_s2mv[o * 64 + sc];
        s0 += xv * w_s2s[o * 64 + sc];
        s1 += xv * w_s2s[(o + 32) * 64 + sc];
    }
    s0 += b_s[o]; s1 += b_s[o + 32];
    for (int r = 0; r < stride; ++r) {
        size_t c = (size_t)p * stride + r;
        const float4* sk = (const float4*)(skip_mv + c * 512 + o * 16);
        float4* om = (float4*)(out_mv + c * 512 + o * 16);
        float4 k0 = sk[0], k1 = sk[1], k2 = sk[2], k3 = sk[3];
        om[0] = make_float4(k0.x + a[0],  k0.y + a[1],  k0.z + a[2],  k0.w + a[3]);
        om[1] = make_float4(k1.x + a[4],  k1.y + a[5],  k1.z + a[6],  k1.w + a[7]);
        om[2] = make_float4(k2.x + a[8],  k2.y + a[9],  k2.z + a[10], k2.w + a[11]);
        om[3] = make_float4(k3.x + a[12], k3.y + a[13], k3.z + a[14], k3.w + a[15]);
        out_s[c * 64 + o]      = skip_s[c * 64 + o] + s0;
        out_s[c * 64 + o + 32] = skip_s[c * 64 + o + 32] + s1;
    }
}

extern "C" void kernel_launch(void* const* d_in, const int* in_sizes, int n_in,
                              void* d_out, int out_size, void* d_ws, size_t ws_size,
                              hipStream_t stream) {
    const float* x_mv    = (const float*)d_in[0];
    const float* x_s     = (const float*)d_in[1];
    const float* skip_mv = (const float*)d_in[2];
    const float* skip_s  = (const float*)d_in[3];
    const float* w_mv    = (const float*)d_in[4];
    const float* w_s2mv  = (const float*)d_in[5];
    const float* w_mv2s  = (const float*)d_in[6];
    const float* w_s2s   = (const float*)d_in[7];
    const float* b_s     = (const float*)d_in[8];

    const int n_parent = in_sizes[0] / 512;
    const int n_child  = in_sizes[2] / 512;
    const int stride   = n_child / n_parent;

    float* out_mv = (float*)d_out;
    float* out_s  = out_mv + (size_t)n_child * 512;
    bf16x8* wsf = (bf16x8*)d_ws;   // 13*256*16 = 53248 B

    build_frags<<<1, THR, 0, stream>>>(w_mv, w_s2mv, w_mv2s, w_s2s, wsf);

    const int full = n_parent >> 5;
    const int rem  = n_parent & 31;
    if (full > 0)
        equi_mfma<<<full, THR, 0, stream>>>(
            x_mv, x_s, skip_mv, skip_s, wsf, b_s,
            out_mv, out_s, n_parent, stride);
    if (rem > 0) {
        int thr = rem * 32;
        int blk = (thr + 255) / 256;
        equi_tail<<<blk, 256, 0, stream>>>(
            x_mv, x_s, skip_mv, skip_s, w_mv, w_s2mv, w_mv2s, w_s2s, b_s,
            out_mv, out_s, full * 32, n_parent, stride);
    }
}

// Round 18
// 149.484 us; speedup vs baseline: 1.6419x; 1.0286x over previous
//
#include <hip/hip_runtime.h>

typedef __attribute__((ext_vector_type(8))) short bf16x8;
typedef __attribute__((ext_vector_type(4))) float f32x4;

#define THR 256
#define PBLK 16

__device__ __forceinline__ unsigned int bf_rne(float f) {
    unsigned int u = __float_as_uint(f);
    u += 0x7fffu + ((u >> 16) & 1u);
    return u >> 16;
}
__device__ __forceinline__ unsigned int pack2(float a, float b) {
    return bf_rne(a) | (bf_rne(b) << 16);
}
__device__ __forceinline__ float bf_lo(unsigned int u) { return __uint_as_float(u << 16); }
__device__ __forceinline__ float bf_hi(unsigned int u) { return __uint_as_float(u & 0xffff0000u); }

#define MFMA(A, B, C) __builtin_amdgcn_mfma_f32_16x16x32_bf16((A), (B), (C), 0, 0, 0)

// xb u16 index (single 16-parent tile): j-stride 520, slot-XOR swizzle
#define XB(j, pl, slot) ((j) * 520 + (pl) * 32 + (slot) * 8)
#define YPS 520   // yb p-stride in u16
#define YSS 68    // ysb p-stride in u16

#define NSLOT 13

// ---- one-block init: build per-thread B fragments once, store [slot][tid] ----
__global__ __launch_bounds__(THR) void build_frags(
    const float* __restrict__ w_mv, const float* __restrict__ w_s2mv,
    const float* __restrict__ w_mv2s, const float* __restrict__ w_s2s,
    bf16x8* __restrict__ wsf)
{
    const int t = threadIdx.x;
    const int lane = t & 63;
    const int wid  = t >> 6;
    const int h   = wid & 1;
    const int jh  = wid >> 1;
    const int col = lane & 15;
    const int g4  = lane >> 4;
    const int kb  = g4 * 8;
    const int oo  = h * 16 + col;

    bf16x8 z;
    #pragma unroll
    for (int e = 0; e < 8; ++e) z[e] = 0;

    #pragma unroll
    for (int gg = 0; gg < 3; ++gg) {
        int b = 2 * jh + gg;
        bf16x8 v = z;
        #pragma unroll
        for (int e = 0; e < 8; ++e)
            v[e] = (short)bf_rne(w_mv[oo * 288 + (kb + e) * 9 + b]);
        wsf[gg * THR + t] = v;
    }
    #pragma unroll
    for (int ww = 0; ww < 2; ++ww) {
        int b = 5 + 2 * jh + ww;
        bf16x8 v = z;
        #pragma unroll
        for (int e = 0; e < 8; ++e)
            v[e] = (short)bf_rne(w_mv[oo * 288 + (kb + e) * 9 + b]);
        wsf[(3 + ww) * THR + t] = v;
    }
    if (jh == 0) {
        #pragma unroll
        for (int c = 0; c < 2; ++c) {
            bf16x8 v = z;
            #pragma unroll
            for (int e = 0; e < 8; ++e)
                v[e] = (short)bf_rne(w_mv2s[((2 * h + c) * 16 + col) * 32 + kb + e]);
            wsf[(5 + c) * THR + t] = v;
        }
        #pragma unroll
        for (int kk = 0; kk < 2; ++kk) {
            bf16x8 v = z;
            #pragma unroll
            for (int e = 0; e < 8; ++e)
                v[e] = (short)bf_rne(w_s2mv[oo * 64 + kk * 32 + kb + e]);
            wsf[(7 + kk) * THR + t] = v;
            #pragma unroll
            for (int c = 0; c < 2; ++c) {
                bf16x8 u = z;
                #pragma unroll
                for (int e = 0; e < 8; ++e)
                    u[e] = (short)bf_rne(w_s2s[((2 * h + c) * 16 + col) * 64 + kk * 32 + kb + e]);
                wsf[(9 + kk * 2 + c) * THR + t] = u;
            }
        }
    } else {
        #pragma unroll
        for (int s = 5; s < NSLOT; ++s) wsf[s * THR + t] = z;
    }
}

__global__ __launch_bounds__(THR) void equi_mfma(
    const float* __restrict__ x_mv,    // [Np,32,16]
    const float* __restrict__ x_s,     // [Np,64]
    const float* __restrict__ skip_mv, // [Nc,32,16]
    const float* __restrict__ skip_s,  // [Nc,64]
    const bf16x8* __restrict__ wsf,    // [13][256] precomputed B fragments
    const float* __restrict__ b_s,     // [64]
    float* __restrict__ out_mv,        // [Nc,32,16]
    float* __restrict__ out_s,         // [Nc,64]
    int n_parent, int stride)
{
    // LDS 18816 B -> up to 8 blocks/CU (32-wave cap).
    // staging view: xb 16640 B (u16[8320]) + xsb 2048 B.
    // epilogue view: yb 16640 B (overlays xb) + ysb 2176 B (overlays xsb).
    __shared__ char smem[18816];
    unsigned short* xb  = (unsigned short*)smem;
    unsigned short* xsb = (unsigned short*)(smem + 16640);
    unsigned short* yb  = (unsigned short*)smem;
    unsigned short* ysb = (unsigned short*)(smem + 16640);

    const int t  = threadIdx.x;
    const int p0 = blockIdx.x * PBLK;

    // ---- stage x_mv -> xb: thread = (p, ig, jq); 8 f4 loads -> 4 ds_write_b128 ----
    {
        const int p  = t >> 4;          // 0..15
        const int ig = (t >> 2) & 3;    // i-group (8 i's)
        const int jq = t & 3;           // j-quad
        const float4* xg = (const float4*)(x_mv + (size_t)p0 * 512);
        bf16x8 acc[4];                  // [jo]
        #pragma unroll
        for (int s = 0; s < 8; ++s) {
            float4 v = xg[p * 128 + (ig * 8 + s) * 4 + jq];
            acc[0][s] = (short)bf_rne(v.x);
            acc[1][s] = (short)bf_rne(v.y);
            acc[2][s] = (short)bf_rne(v.z);
            acc[3][s] = (short)bf_rne(v.w);
        }
        const int slot = ig ^ (p & 3) ^ jq;
        #pragma unroll
        for (int jo = 0; jo < 4; ++jo)
            *(bf16x8*)&xb[XB(jq * 4 + jo, p, slot)] = acc[jo];

        // x_s -> xsb: thread = (p, q); 1 f4 load -> 1 ds_write_b64
        const int q  = t & 15;
        const float4* xsg = (const float4*)(x_s + (size_t)p0 * 64);
        float4 v0 = xsg[p * 16 + q];
        unsigned short* dst = &xsb[(p * 8 + ((q >> 1) ^ (p & 7))) * 8 + (q & 1) * 4];
        dst[0] = (unsigned short)bf_rne(v0.x);
        dst[1] = (unsigned short)bf_rne(v0.y);
        dst[2] = (unsigned short)bf_rne(v0.z);
        dst[3] = (unsigned short)bf_rne(v0.w);
    }

    // ---- load precomputed B fragments: 13 coalesced dwordx4 (L2-hot) ----
    const int lane = t & 63;
    const int wid  = t >> 6;
    const int h   = wid & 1;
    const int jh  = wid >> 1;
    const int col = lane & 15;
    const int g4  = lane >> 4;
    const int oo  = h * 16 + col;

    bf16x8 Bg[3], Bw[2], Bm2s[2], Bs2mv[2], Bs2s[2][2];
    Bg[0]      = wsf[0 * THR + t];
    Bg[1]      = wsf[1 * THR + t];
    Bg[2]      = wsf[2 * THR + t];
    Bw[0]      = wsf[3 * THR + t];
    Bw[1]      = wsf[4 * THR + t];
    Bm2s[0]    = wsf[5 * THR + t];
    Bm2s[1]    = wsf[6 * THR + t];
    Bs2mv[0]   = wsf[7 * THR + t];
    Bs2mv[1]   = wsf[8 * THR + t];
    Bs2s[0][0] = wsf[9 * THR + t];
    Bs2s[0][1] = wsf[10 * THR + t];
    Bs2s[1][0] = wsf[11 * THR + t];
    Bs2s[1][1] = wsf[12 * THR + t];

    __syncthreads();   // barrier #1: xb/xsb ready

    // ---- MFMA phase (single 16-parent tile) ----
    f32x4 cj[8];
    f32x4 cs[2];
    #pragma unroll
    for (int jj = 0; jj < 8; ++jj) cj[jj] = (f32x4){0.f, 0.f, 0.f, 0.f};
    cs[0] = (f32x4){0.f, 0.f, 0.f, 0.f};
    cs[1] = (f32x4){0.f, 0.f, 0.f, 0.f};
    const int prow = col;

    if (jh == 0) {
        bf16x8 A0;
        #pragma unroll
        for (int jj = 0; jj < 8; ++jj) {
            int slot = g4 ^ (prow & 3) ^ (jj >> 2);
            bf16x8 A = *(const bf16x8*)&xb[XB(jj, prow, slot)];
            if (jj == 0)      cj[0] = MFMA(A, Bg[0], cj[0]);
            else if (jj < 5)  cj[jj] = MFMA(A, Bg[1], cj[jj]);
            else              cj[jj] = MFMA(A, Bg[2], cj[jj]);
            if (jj == 0) { cj[1] = MFMA(A, Bw[0], cj[1]); A0 = A; }
            else if (jj == 2) cj[5] = MFMA(A, Bw[1], cj[5]);
            else if (jj == 3) cj[6] = MFMA(A, Bw[1], cj[6]);
            else if (jj == 4) cj[7] = MFMA(A, Bw[1], cj[7]);
        }
        cs[0] = MFMA(A0, Bm2s[0], cs[0]);
        cs[1] = MFMA(A0, Bm2s[1], cs[1]);
        #pragma unroll
        for (int kk = 0; kk < 2; ++kk) {
            const unsigned short* sp = &xsb[(prow * 8 + ((kk * 4 + g4) ^ (prow & 7))) * 8];
            bf16x8 Axs = *(const bf16x8*)sp;
            cj[0] = MFMA(Axs, Bs2mv[kk], cj[0]);
            cs[0] = MFMA(Axs, Bs2s[kk][0], cs[0]);
            cs[1] = MFMA(Axs, Bs2s[kk][1], cs[1]);
        }
    } else {
        #pragma unroll
        for (int jj = 0; jj < 8; ++jj) {
            int j = 8 + jj;
            int slot = g4 ^ (prow & 3) ^ (j >> 2);
            bf16x8 A = *(const bf16x8*)&xb[XB(j, prow, slot)];
            if (jj < 3)       cj[jj] = MFMA(A, Bg[0], cj[jj]);
            else if (jj < 7)  cj[jj] = MFMA(A, Bg[1], cj[jj]);
            else              cj[jj] = MFMA(A, Bg[2], cj[jj]);
            if (jj == 0)      cj[3] = MFMA(A, Bw[0], cj[3]);
            else if (jj == 1) cj[4] = MFMA(A, Bw[0], cj[4]);
            else if (jj == 2) cj[5] = MFMA(A, Bw[0], cj[5]);
            else if (jj == 6) cj[7] = MFMA(A, Bw[1], cj[7]);
        }
    }

    // ---- single transpose: C -> yb/ysb (bf16); accumulators die here ----
    __syncthreads();   // barrier #2: all xb/xsb reads complete (yb overlays xb)
    #pragma unroll
    for (int r = 0; r < 4; ++r) {
        int p = g4 * 4 + r;
        #pragma unroll
        for (int q4 = 0; q4 < 2; ++q4) {
            int jqg  = jh * 2 + q4;
            int quad = jqg ^ (oo & 3) ^ (col >> 2) ^ g4;   // g4 == p>>2
            uint2 w;
            w.x = pack2(cj[q4 * 4 + 0][r], cj[q4 * 4 + 1][r]);
            w.y = pack2(cj[q4 * 4 + 2][r], cj[q4 * 4 + 3][r]);
            *(uint2*)&yb[p * YPS + oo * 16 + quad * 4] = w;
        }
    }
    if (jh == 0) {
        #pragma unroll
        for (int c = 0; c < 2; ++c)
            #pragma unroll
            for (int r = 0; r < 4; ++r)
                ysb[(g4 * 4 + r) * YSS + (2 * h + c) * 16 + col] =
                    (unsigned short)bf_rne(cs[c][r]);
    }
    __syncthreads();   // barrier #3: yb/ysb ready

    // ---- streaming epilogue: batch-8 pipelined stream ----
    const int cbase = p0 * stride;
    const float4* sk4 = (const float4*)skip_mv;
    float4* om4 = (float4*)out_mv;
    const float4* sks4 = (const float4*)skip_s;
    float4* os4 = (float4*)out_s;
    const float4* bs4 = (const float4*)b_s;

    if (stride == 2) {
        // mv: 16p*2c*128 f4 = 4096 / 256 thr = 16 iters -> 2 batches of 8
        #pragma unroll
        for (int bt = 0; bt < 2; ++bt) {
            size_t gidx[8];
            float4 sv[8];
            uint2  yv[8];
            #pragma unroll
            for (int u = 0; u < 8; ++u) {
                int id = t + (bt * 8 + u) * THR;
                int child = id >> 7, rem = id & 127;
                int o = rem >> 2, q = rem & 3;
                int ph = child >> 1;
                int quad = q ^ (o & 3) ^ ((o >> 2) & 3) ^ ((ph >> 2) & 3);
                gidx[u] = (size_t)(cbase + child) * 128 + rem;
                sv[u] = sk4[gidx[u]];
                yv[u] = *(const uint2*)&yb[ph * YPS + o * 16 + quad * 4];
            }
            #pragma unroll
            for (int u = 0; u < 8; ++u)
                om4[gidx[u]] = make_float4(sv[u].x + bf_lo(yv[u].x), sv[u].y + bf_hi(yv[u].x),
                                           sv[u].z + bf_lo(yv[u].y), sv[u].w + bf_hi(yv[u].y));
        }
        // s: 16p*2c*16 f4 = 512 / 256 = 2 iters -> 1 batch of 2
        {
            size_t gidx[2];
            float4 sv[2], av[2];
            #pragma unroll
            for (int u = 0; u < 2; ++u) {
                int id = t + u * THR;
                int child = id >> 4, ch4 = id & 15;
                int ph = child >> 1;
                uint2 yv = *(const uint2*)&ysb[ph * YSS + ch4 * 4];
                float4 bb = bs4[ch4];
                av[u] = make_float4(bf_lo(yv.x) + bb.x, bf_hi(yv.x) + bb.y,
                                    bf_lo(yv.y) + bb.z, bf_hi(yv.y) + bb.w);
                gidx[u] = (size_t)(cbase + child) * 16 + ch4;
                sv[u] = sks4[gidx[u]];
            }
            #pragma unroll
            for (int u = 0; u < 2; ++u)
                os4[gidx[u]] = make_float4(sv[u].x + av[u].x, sv[u].y + av[u].y,
                                           sv[u].z + av[u].z, sv[u].w + av[u].w);
        }
    } else {
        const int totmv = PBLK * stride * 128;
        for (int id = t; id < totmv; id += THR) {
            int child = id >> 7, rem = id & 127;
            int o = rem >> 2, q = rem & 3;
            int ph = child / stride;
            int quad = q ^ (o & 3) ^ ((o >> 2) & 3) ^ ((ph >> 2) & 3);
            uint2 yv = *(const uint2*)&yb[ph * YPS + o * 16 + quad * 4];
            size_t gi = (size_t)(cbase + child) * 128 + rem;
            float4 s = sk4[gi];
            om4[gi] = make_float4(s.x + bf_lo(yv.x), s.y + bf_hi(yv.x),
                                  s.z + bf_lo(yv.y), s.w + bf_hi(yv.y));
        }
        const int tots = PBLK * stride * 16;
        for (int id = t; id < tots; id += THR) {
            int child = id >> 4, ch4 = id & 15;
            int ph = child / stride;
            uint2 yv = *(const uint2*)&ysb[ph * YSS + ch4 * 4];
            float4 bb = bs4[ch4];
            size_t gi = (size_t)(cbase + child) * 16 + ch4;
            float4 s = sks4[gi];
            os4[gi] = make_float4(s.x + bf_lo(yv.x) + bb.x, s.y + bf_hi(yv.x) + bb.y,
                                  s.z + bf_lo(yv.y) + bb.z, s.w + bf_hi(yv.y) + bb.w);
        }
    }
}

// remainder parents (n_parent % 16): slow scalar path, f32, direct global
__global__ __launch_bounds__(256) void equi_tail(
    const float* __restrict__ x_mv, const float* __restrict__ x_s,
    const float* __restrict__ skip_mv, const float* __restrict__ skip_s,
    const float* __restrict__ w_mv, const float* __restrict__ w_s2mv,
    const float* __restrict__ w_mv2s, const float* __restrict__ w_s2s,
    const float* __restrict__ b_s,
    float* __restrict__ out_mv, float* __restrict__ out_s,
    int pstart, int n_parent, int stride)
{
    int idx = blockIdx.x * blockDim.x + threadIdx.x;
    int o = idx & 31, pr = idx >> 5;
    int p = pstart + pr;
    if (p >= n_parent) return;
    float a[16];
    #pragma unroll
    for (int j = 0; j < 16; ++j) a[j] = 0.f;
    float s0 = 0.f, s1 = 0.f;
    const float4* xg = (const float4*)(x_mv + (size_t)p * 512);
    for (int i = 0; i < 32; ++i) {
        float4 X0 = xg[i * 4 + 0], X1 = xg[i * 4 + 1], X2 = xg[i * 4 + 2], X3 = xg[i * 4 + 3];
        const float* wp = &w_mv[o * 288 + i * 9];
        float w0 = wp[0], w1 = wp[1], w2 = wp[2], w3 = wp[3], w4 = wp[4];
        float w5 = wp[5], w6 = wp[6], w7 = wp[7], w8 = wp[8];
        a[0] += X0.x * w0;  a[1] += X0.y * w1 + X0.x * w5;
        a[2] += X0.z * w1;  a[3] += X0.w * w1;  a[4] += X1.x * w1;
        a[5] += X1.y * w2 + X0.z * w6;  a[6] += X1.z * w2 + X0.w * w6;
        a[7] += X1.w * w2 + X1.x * w6;  a[8] += X2.x * w2;
        a[9] += X2.y * w2;  a[10] += X2.z * w2;
        a[11] += X2.w * w3 + X2.x * w7;  a[12] += X3.x * w3 + X2.y * w7;
        a[13] += X3.y * w3 + X2.z * w7;  a[14] += X3.z * w3;
        a[15] += X3.w * w4 + X3.z * w8;
        s0 += X0.x * w_mv2s[o * 32 + i];
        s1 += X0.x * w_mv2s[(o + 32) * 32 + i];
    }
    for (int sc = 0; sc < 64; ++sc) {
        float xv = x_s[(size_t)p * 64 + sc];
        a[0] += xv * w_s2mv[o * 64 + sc];
        s0 += xv * w_s2s[o * 64 + sc];
        s1 += xv * w_s2s[(o + 32) * 64 + sc];
    }
    s0 += b_s[o]; s1 += b_s[o + 32];
    for (int r = 0; r < stride; ++r) {
        size_t c = (size_t)p * stride + r;
        const float4* sk = (const float4*)(skip_mv + c * 512 + o * 16);
        float4* om = (float4*)(out_mv + c * 512 + o * 16);
        float4 k0 = sk[0], k1 = sk[1], k2 = sk[2], k3 = sk[3];
        om[0] = make_float4(k0.x + a[0],  k0.y + a[1],  k0.z + a[2],  k0.w + a[3]);
        om[1] = make_float4(k1.x + a[4],  k1.y + a[5],  k1.z + a[6],  k1.w + a[7]);
        om[2] = make_float4(k2.x + a[8],  k2.y + a[9],  k2.z + a[10], k2.w + a[11]);
        om[3] = make_float4(k3.x + a[12], k3.y + a[13], k3.z + a[14], k3.w + a[15]);
        out_s[c * 64 + o]      = skip_s[c * 64 + o] + s0;
        out_s[c * 64 + o + 32] = skip_s[c * 64 + o + 32] + s1;
    }
}

extern "C" void kernel_launch(void* const* d_in, const int* in_sizes, int n_in,
                              void* d_out, int out_size, void* d_ws, size_t ws_size,
                              hipStream_t stream) {
    const float* x_mv    = (const float*)d_in[0];
    const float* x_s     = (const float*)d_in[1];
    const float* skip_mv = (const float*)d_in[2];
    const float* skip_s  = (const float*)d_in[3];
    const float* w_mv    = (const float*)d_in[4];
    const float* w_s2mv  = (const float*)d_in[5];
    const float* w_mv2s  = (const float*)d_in[6];
    const float* w_s2s   = (const float*)d_in[7];
    const float* b_s     = (const float*)d_in[8];

    const int n_parent = in_sizes[0] / 512;
    const int n_child  = in_sizes[2] / 512;
    const int stride   = n_child / n_parent;

    float* out_mv = (float*)d_out;
    float* out_s  = out_mv + (size_t)n_child * 512;
    bf16x8* wsf = (bf16x8*)d_ws;   // 13*256*16 = 53248 B

    build_frags<<<1, THR, 0, stream>>>(w_mv, w_s2mv, w_mv2s, w_s2s, wsf);

    const int full = n_parent >> 4;            // blocks of 16 parents
    const int rem  = n_parent & 15;
    if (full > 0)
        equi_mfma<<<full, THR, 0, stream>>>(
            x_mv, x_s, skip_mv, skip_s, wsf, b_s,
            out_mv, out_s, n_parent, stride);
    if (rem > 0) {
        int thr = rem * 32;
        int blk = (thr + 255) / 256;
        equi_tail<<<blk, 256, 0, stream>>>(
            x_mv, x_s, skip_mv, skip_s, w_mv, w_s2mv, w_mv2s, w_s2s, b_s,
            out_mv, out_s, full * 16, n_parent, stride);
    }
}